// Round 1
// baseline (26037.091 us; speedup 1.0000x reference)
//
#include <hip/hip_runtime.h>
#include <hip/hip_bf16.h>

#define B_     32
#define NTOK   197
#define NPATCH 196
#define D_     768
#define H_     12
#define HD_    64
#define DEPTH_ 12
#define MLPD_  3072
#define TASKS_ 10
#define PL_    5
#define NPL_   5
#define SCALE_ 0.125f
#define ROWS   (B_*NTOK)   // 6304

// ---------- helpers ----------
__device__ inline unsigned int f2bf(float f){
  unsigned int u = __float_as_uint(f);
  return (u + 0x7fffu + ((u >> 16) & 1u)) >> 16;   // RNE to bf16 (low 16 bits)
}
__device__ inline float bflo(unsigned int u){ return __uint_as_float(u << 16); }
__device__ inline float bfhi(unsigned int u){ return __uint_as_float(u & 0xffff0000u); }
__device__ inline float gelu_f(float x){ return 0.5f * x * (1.f + erff(x * 0.70710678118f)); }

// ---------- im2col for patch embedding ----------
__global__ __launch_bounds__(256) void im2col_kernel(const float* __restrict__ x,
                                                     float* __restrict__ out)
{
  int idx = blockIdx.x * 256 + threadIdx.x;
  const int tot = B_ * NPATCH * D_;
  if (idx >= tot) return;
  int m = idx / D_, k = idx - m * D_;
  int b = m / NPATCH, p = m - b * NPATCH;
  int pr = p / 14, pc = p - pr * 14;
  int c = k >> 8, r = k & 255;
  int py = r >> 4, px = r & 15;
  out[idx] = x[(((size_t)(b * 3 + c) * 224) + pr * 16 + py) * 224 + pc * 16 + px];
}

// ---------- assemble h0 = [cls; patches+patch_b] + pos ----------
__global__ __launch_bounds__(256) void assemble_kernel(const float* __restrict__ pe,
    const float* __restrict__ patch_b, const float* __restrict__ cls,
    const float* __restrict__ pos, float* __restrict__ h)
{
  int idx = blockIdx.x * 256 + threadIdx.x;
  const int tot = ROWS * D_;
  if (idx >= tot) return;
  int bn = idx / D_, d = idx - bn * D_;
  int b = bn / NTOK, n = bn - b * NTOK;
  float v;
  if (n == 0) v = cls[d];
  else        v = pe[((size_t)b * NPATCH + (n - 1)) * D_ + d] + patch_b[d];
  h[idx] = v + pos[(size_t)n * D_ + d];
}

// ---------- LayerNorm (one block per row) ----------
__global__ __launch_bounds__(256) void ln_kernel(const float* __restrict__ x, size_t xstride,
    const float* __restrict__ w, const float* __restrict__ b,
    float* __restrict__ y, size_t ystride)
{
  const float* xr = x + (size_t)blockIdx.x * xstride;
  float vals[3];
  float s = 0.f, ss = 0.f;
  #pragma unroll
  for (int t = 0; t < 3; t++) {
    float v = xr[threadIdx.x + t * 256];
    vals[t] = v; s += v; ss += v * v;
  }
  #pragma unroll
  for (int off = 32; off >= 1; off >>= 1) {
    s  += __shfl_down(s, off);
    ss += __shfl_down(ss, off);
  }
  __shared__ float sm[4], ssm[4];
  int wid = threadIdx.x >> 6, lane = threadIdx.x & 63;
  if (lane == 0) { sm[wid] = s; ssm[wid] = ss; }
  __syncthreads();
  s  = sm[0] + sm[1] + sm[2] + sm[3];
  ss = ssm[0] + ssm[1] + ssm[2] + ssm[3];
  float mean = s * (1.f / D_);
  float var  = ss * (1.f / D_) - mean * mean;
  float inv  = rsqrtf(var + 1e-6f);
  float* yr = y + (size_t)blockIdx.x * ystride;
  #pragma unroll
  for (int t = 0; t < 3; t++) {
    int d = threadIdx.x + t * 256;
    yr[d] = (vals[t] - mean) * inv * w[d] + b[d];
  }
}

// ---------- generic GEMM: C[m,n] = act( sum_k A[m,k]*W[n,k] + bias[n] ) (+ resid) ----------
#define BM 64
#define BN 64
#define BK 16

template<int ACT, int HASRES>
__global__ __launch_bounds__(256) void gemm_bt(
    const float* __restrict__ A, const float* __restrict__ W,
    const float* __restrict__ bias, const float* __restrict__ resid,
    float* __restrict__ C, int M, int Nn, int K)
{
  __shared__ float As[BK][BM + 1];
  __shared__ float Ws[BK][BN + 1];
  const int bm = blockIdx.y * BM, bn = blockIdx.x * BN;
  const int tx = threadIdx.x & 15, ty = threadIdx.x >> 4;
  float acc[4][4] = {};
  for (int k0 = 0; k0 < K; k0 += BK) {
    #pragma unroll
    for (int t = 0; t < 4; t++) {
      int e = threadIdx.x + t * 256;
      int r = e >> 4, kk = e & 15;
      int m = bm + r;
      As[kk][r] = (m < M) ? A[(size_t)m * K + k0 + kk] : 0.f;
      Ws[kk][r] = W[(size_t)(bn + r) * K + k0 + kk];
    }
    __syncthreads();
    #pragma unroll
    for (int kk = 0; kk < BK; kk++) {
      float a[4], w[4];
      #pragma unroll
      for (int i = 0; i < 4; i++) a[i] = As[kk][ty * 4 + i];
      #pragma unroll
      for (int j = 0; j < 4; j++) w[j] = Ws[kk][tx * 4 + j];
      #pragma unroll
      for (int i = 0; i < 4; i++)
        #pragma unroll
        for (int j = 0; j < 4; j++)
          acc[i][j] = fmaf(a[i], w[j], acc[i][j]);
    }
    __syncthreads();
  }
  #pragma unroll
  for (int i = 0; i < 4; i++) {
    int m = bm + ty * 4 + i;
    if (m < M) {
      #pragma unroll
      for (int j = 0; j < 4; j++) {
        int n = bn + tx * 4 + j;
        float v = acc[i][j];
        if (bias) v += bias[n];
        if (ACT == 1) v = gelu_f(v);
        if (HASRES) v += resid[(size_t)m * Nn + n];
        C[(size_t)m * Nn + n] = v;
      }
    }
  }
}

// ---------- fused attention: one block per (b, head) ----------
__device__ inline float dot64(const float* q, const unsigned int* krow)
{
  float s = 0.f;
  const uint4* kp = (const uint4*)krow;
  #pragma unroll
  for (int w = 0; w < 8; w++) {
    uint4 u = kp[w];
    s = fmaf(q[w*8+0], bflo(u.x), s); s = fmaf(q[w*8+1], bfhi(u.x), s);
    s = fmaf(q[w*8+2], bflo(u.y), s); s = fmaf(q[w*8+3], bfhi(u.y), s);
    s = fmaf(q[w*8+4], bflo(u.z), s); s = fmaf(q[w*8+5], bfhi(u.z), s);
    s = fmaf(q[w*8+6], bflo(u.w), s); s = fmaf(q[w*8+7], bfhi(u.w), s);
  }
  return s;
}

__global__ __launch_bounds__(256) void attn_kernel(
    const float* __restrict__ qkv, const float* __restrict__ prefix_k,
    const float* __restrict__ prefix_v, const float* __restrict__ act_scale,
    const int* __restrict__ task_id, float* __restrict__ out,
    int layer, int hasprefix)
{
  __shared__ unsigned int Ks[PL_ + NTOK][HD_ / 2];
  __shared__ unsigned int Vs[PL_ + NTOK][HD_ / 2];
  const int b = blockIdx.x / H_, h = blockIdx.x % H_;
  const int Kt = hasprefix ? (PL_ + NTOK) : NTOK;

  int tsk = 0;
  if (hasprefix) {
    tsk = task_id[b];
    tsk = tsk < 0 ? 0 : (tsk > TASKS_ - 1 ? TASKS_ - 1 : tsk);
  }

  for (int idx = threadIdx.x; idx < Kt * (HD_ / 2); idx += 256) {
    int j = idx >> 5, dw = idx & 31, d = dw * 2;
    float k0, k1, v0, v1;
    if (hasprefix && j < PL_) {
      size_t off = ((((size_t)layer * TASKS_ + tsk) * PL_ + j) * H_ + h) * HD_ + d;
      k0 = prefix_k[off]; k1 = prefix_k[off + 1];
      v0 = prefix_v[off]; v1 = prefix_v[off + 1];
    } else {
      int n = hasprefix ? (j - PL_) : j;
      size_t off = ((size_t)b * NTOK + n) * (3 * D_) + (size_t)h * HD_ + d;
      k0 = qkv[off + D_];     k1 = qkv[off + D_ + 1];
      v0 = qkv[off + 2 * D_]; v1 = qkv[off + 2 * D_ + 1];
    }
    Ks[j][dw] = f2bf(k0) | (f2bf(k1) << 16);
    Vs[j][dw] = f2bf(v0) | (f2bf(v1) << 16);
  }
  __syncthreads();

  const int qr = threadIdx.x;
  if (qr >= NTOK) return;

  float q[HD_];
  {
    const float* qp = qkv + ((size_t)b * NTOK + qr) * (3 * D_) + (size_t)h * HD_;
    #pragma unroll
    for (int d = 0; d < HD_; d++) q[d] = qp[d] * SCALE_;
  }
  float s0 = 1.f, s1 = 1.f;
  if (hasprefix) { s0 = act_scale[layer * 2]; s1 = act_scale[layer * 2 + 1]; }

  // pass 1: max
  float mx = -1e30f;
  for (int j = 0; j < Kt; j++) {
    float s = dot64(q, Ks[j]);
    if (hasprefix && j < PL_) s += s1 / (1.f + __expf(-s * s0));
    mx = fmaxf(mx, s);
  }
  // pass 2: sum + PV
  float l = 0.f;
  float o[HD_];
  #pragma unroll
  for (int d = 0; d < HD_; d++) o[d] = 0.f;
  for (int j = 0; j < Kt; j++) {
    float s = dot64(q, Ks[j]);
    if (hasprefix && j < PL_) s += s1 / (1.f + __expf(-s * s0));
    float p = __expf(s - mx);
    l += p;
    const uint4* vp = (const uint4*)Vs[j];
    #pragma unroll
    for (int w = 0; w < 8; w++) {
      uint4 u = vp[w];
      o[w*8+0] = fmaf(p, bflo(u.x), o[w*8+0]); o[w*8+1] = fmaf(p, bfhi(u.x), o[w*8+1]);
      o[w*8+2] = fmaf(p, bflo(u.y), o[w*8+2]); o[w*8+3] = fmaf(p, bfhi(u.y), o[w*8+3]);
      o[w*8+4] = fmaf(p, bflo(u.z), o[w*8+4]); o[w*8+5] = fmaf(p, bfhi(u.z), o[w*8+5]);
      o[w*8+6] = fmaf(p, bflo(u.w), o[w*8+6]); o[w*8+7] = fmaf(p, bfhi(u.w), o[w*8+7]);
    }
  }
  float inv = 1.f / l;
  float* op = out + ((size_t)b * NTOK + qr) * D_ + (size_t)h * HD_;
  #pragma unroll
  for (int d = 0; d < HD_; d++) op[d] = o[d] * inv;
}

// ---------- launch ----------
extern "C" void kernel_launch(void* const* d_in, const int* in_sizes, int n_in,
                              void* d_out, int out_size, void* d_ws, size_t ws_size,
                              hipStream_t stream)
{
  (void)in_sizes; (void)n_in; (void)out_size; (void)ws_size;
  const float* x         = (const float*)d_in[0];
  const int*   task_id   = (const int*)  d_in[1];
  const float* patch_w   = (const float*)d_in[2];
  const float* patch_b   = (const float*)d_in[3];
  const float* cls_token = (const float*)d_in[4];
  const float* pos_embed = (const float*)d_in[5];
  const float* ln1_w     = (const float*)d_in[6];
  const float* ln1_b     = (const float*)d_in[7];
  const float* qkv_w     = (const float*)d_in[8];
  const float* qkv_b     = (const float*)d_in[9];
  const float* proj_w    = (const float*)d_in[10];
  const float* proj_b    = (const float*)d_in[11];
  const float* ln2_w     = (const float*)d_in[12];
  const float* ln2_b     = (const float*)d_in[13];
  const float* fc1_w     = (const float*)d_in[14];
  const float* fc1_b     = (const float*)d_in[15];
  const float* fc2_w     = (const float*)d_in[16];
  const float* fc2_b     = (const float*)d_in[17];
  const float* norm_w    = (const float*)d_in[18];
  const float* norm_b    = (const float*)d_in[19];
  const float* prefix_k  = (const float*)d_in[20];
  const float* prefix_v  = (const float*)d_in[21];
  const float* act_scale = (const float*)d_in[22];
  float* out = (float*)d_out;

  float* h     = (float*)d_ws;                         // ROWS*D
  float* bufB  = h    + (size_t)ROWS * D_;             // ROWS*D   (xn / attn_out)
  float* bufC  = bufB + (size_t)ROWS * D_;             // ROWS*MLPD (qkv / mlp / im2col+pe)
  float* im2c  = bufC;
  float* peout = bufC + (size_t)B_ * NPATCH * D_;

  // ---- patch embedding ----
  {
    int tot = B_ * NPATCH * D_;
    im2col_kernel<<<(tot + 255) / 256, 256, 0, stream>>>(x, im2c);
  }
  gemm_bt<0,0><<<dim3(D_ / BN, (B_ * NPATCH + BM - 1) / BM), 256, 0, stream>>>(
      im2c, patch_w, nullptr, nullptr, peout, B_ * NPATCH, D_, D_);
  {
    int tot = ROWS * D_;
    assemble_kernel<<<(tot + 255) / 256, 256, 0, stream>>>(peout, patch_b, cls_token, pos_embed, h);
  }

  // ---- transformer layers ----
  for (int i = 0; i < DEPTH_; i++) {
    ln_kernel<<<ROWS, 256, 0, stream>>>(h, D_, ln1_w + i * D_, ln1_b + i * D_, bufB, D_);
    gemm_bt<0,0><<<dim3(3 * D_ / BN, (ROWS + BM - 1) / BM), 256, 0, stream>>>(
        bufB, qkv_w + (size_t)i * 3 * D_ * D_, qkv_b + i * 3 * D_, nullptr, bufC, ROWS, 3 * D_, D_);
    int hp = (i < NPL_) ? 1 : 0;
    attn_kernel<<<B_ * H_, 256, 0, stream>>>(bufC, prefix_k, prefix_v, act_scale, task_id, bufB, i, hp);
    gemm_bt<0,1><<<dim3(D_ / BN, (ROWS + BM - 1) / BM), 256, 0, stream>>>(
        bufB, proj_w + (size_t)i * D_ * D_, proj_b + i * D_, h, h, ROWS, D_, D_);
    ln_kernel<<<ROWS, 256, 0, stream>>>(h, D_, ln2_w + i * D_, ln2_b + i * D_, bufB, D_);
    gemm_bt<1,0><<<dim3(MLPD_ / BN, (ROWS + BM - 1) / BM), 256, 0, stream>>>(
        bufB, fc1_w + (size_t)i * MLPD_ * D_, fc1_b + i * MLPD_, nullptr, bufC, ROWS, MLPD_, D_);
    gemm_bt<0,1><<<dim3(D_ / BN, (ROWS + BM - 1) / BM), 256, 0, stream>>>(
        bufC, fc2_w + (size_t)i * D_ * MLPD_, fc2_b + i * D_, h, h, ROWS, D_, MLPD_);
  }

  // ---- final LN on token 0 only ----
  ln_kernel<<<B_, 256, 0, stream>>>(h, (size_t)NTOK * D_, norm_w, norm_b, out, D_);
}

// Round 2
// 6720.231 us; speedup vs baseline: 3.8744x; 3.8744x over previous
//
#include <hip/hip_runtime.h>
#include <hip/hip_bf16.h>

#define B_     32
#define NTOK   197
#define NPATCH 196
#define D_     768
#define H_     12
#define HD_    64
#define DEPTH_ 12
#define MLPD_  3072
#define TASKS_ 10
#define PL_    5
#define NPL_   5
#define SCALE_ 0.125f
#define ROWS   (B_*NTOK)   // 6304

typedef unsigned short ushortT;
typedef __bf16 bf16x8 __attribute__((ext_vector_type(8)));
typedef float  f32x4  __attribute__((ext_vector_type(4)));

// ---------- helpers ----------
__device__ inline unsigned int f2bf(float f){
  unsigned int u = __float_as_uint(f);
  return (u + 0x7fffu + ((u >> 16) & 1u)) >> 16;   // RNE to bf16
}
__device__ inline float bflo(unsigned int u){ return __uint_as_float(u << 16); }
__device__ inline float bfhi(unsigned int u){ return __uint_as_float(u & 0xffff0000u); }
__device__ inline float bf2f(ushortT u){ return __uint_as_float(((unsigned int)u) << 16); }
__device__ inline float gelu_f(float x){ return 0.5f * x * (1.f + erff(x * 0.70710678118f)); }

__device__ inline void gload16(const void* g, void* l){
  __builtin_amdgcn_global_load_lds(
      (const __attribute__((address_space(1))) void*)(uintptr_t)g,
      (__attribute__((address_space(3))) void*)(uintptr_t)l,
      16, 0, 0);
}

// ---------- weight conversion fp32 -> bf16 ----------
__global__ __launch_bounds__(256) void convw4_kernel(const float* __restrict__ s0,
    const float* __restrict__ s1, const float* __restrict__ s2, const float* __restrict__ s3,
    ushortT* __restrict__ dst)
{
  int idx = blockIdx.x * 256 + threadIdx.x;
  int e = idx * 8;
  if (e >= 7077888) return;
  const float* s; int loc;
  if (e < 1769472)      { s = s0; loc = e; }
  else if (e < 2359296) { s = s1; loc = e - 1769472; }
  else if (e < 4718592) { s = s2; loc = e - 2359296; }
  else                  { s = s3; loc = e - 4718592; }
  float4 a = *(const float4*)(s + loc);
  float4 c = *(const float4*)(s + loc + 4);
  uint4 o;
  o.x = f2bf(a.x) | (f2bf(a.y) << 16);
  o.y = f2bf(a.z) | (f2bf(a.w) << 16);
  o.z = f2bf(c.x) | (f2bf(c.y) << 16);
  o.w = f2bf(c.z) | (f2bf(c.w) << 16);
  *(uint4*)(dst + e) = o;
}

__global__ __launch_bounds__(256) void convw1_kernel(const float* __restrict__ s,
    ushortT* __restrict__ dst, int n8)
{
  int idx = blockIdx.x * 256 + threadIdx.x;
  if (idx >= n8) return;
  int e = idx * 8;
  float4 a = *(const float4*)(s + e);
  float4 c = *(const float4*)(s + e + 4);
  uint4 o;
  o.x = f2bf(a.x) | (f2bf(a.y) << 16);
  o.y = f2bf(a.z) | (f2bf(a.w) << 16);
  o.z = f2bf(c.x) | (f2bf(c.y) << 16);
  o.w = f2bf(c.z) | (f2bf(c.w) << 16);
  *(uint4*)(dst + e) = o;
}

// ---------- im2col (bf16 out) ----------
__global__ __launch_bounds__(256) void im2col_kernel(const float* __restrict__ x,
                                                     ushortT* __restrict__ out)
{
  int idx = blockIdx.x * 256 + threadIdx.x;
  const int tot = B_ * NPATCH * D_;
  if (idx >= tot) return;
  int m = idx / D_, k = idx - m * D_;
  int b = m / NPATCH, p = m - b * NPATCH;
  int pr = p / 14, pc = p - pr * 14;
  int c = k >> 8, r = k & 255;
  int py = r >> 4, px = r & 15;
  float v = x[(((size_t)(b * 3 + c) * 224) + pr * 16 + py) * 224 + pc * 16 + px];
  out[idx] = (ushortT)f2bf(v);
}

// ---------- assemble h0 = [cls; patches+patch_b] + pos (fp32) ----------
__global__ __launch_bounds__(256) void assemble_kernel(const float* __restrict__ pe,
    const float* __restrict__ patch_b, const float* __restrict__ cls,
    const float* __restrict__ pos, float* __restrict__ h)
{
  int idx = blockIdx.x * 256 + threadIdx.x;
  const int tot = ROWS * D_;
  if (idx >= tot) return;
  int bn = idx / D_, d = idx - bn * D_;
  int b = bn / NTOK, n = bn - b * NTOK;
  float v;
  if (n == 0) v = cls[d];
  else        v = pe[((size_t)b * NPATCH + (n - 1)) * D_ + d] + patch_b[d];
  h[idx] = v + pos[(size_t)n * D_ + d];
}

// ---------- LayerNorm (one block per row), templated output ----------
template<int OUTBF>
__global__ __launch_bounds__(256) void ln_kernel(const float* __restrict__ x, size_t xstride,
    const float* __restrict__ w, const float* __restrict__ b,
    void* __restrict__ y, size_t ystride)
{
  const float* xr = x + (size_t)blockIdx.x * xstride;
  float vals[3];
  float s = 0.f, ss = 0.f;
  #pragma unroll
  for (int t = 0; t < 3; t++) {
    float v = xr[threadIdx.x + t * 256];
    vals[t] = v; s += v; ss += v * v;
  }
  #pragma unroll
  for (int off = 32; off >= 1; off >>= 1) {
    s  += __shfl_down(s, off);
    ss += __shfl_down(ss, off);
  }
  __shared__ float sm[4], ssm[4];
  int wid = threadIdx.x >> 6, lane = threadIdx.x & 63;
  if (lane == 0) { sm[wid] = s; ssm[wid] = ss; }
  __syncthreads();
  s  = sm[0] + sm[1] + sm[2] + sm[3];
  ss = ssm[0] + ssm[1] + ssm[2] + ssm[3];
  float mean = s * (1.f / D_);
  float var  = ss * (1.f / D_) - mean * mean;
  float inv  = rsqrtf(var + 1e-6f);
  #pragma unroll
  for (int t = 0; t < 3; t++) {
    int d = threadIdx.x + t * 256;
    float v = (vals[t] - mean) * inv * w[d] + b[d];
    if (OUTBF) ((ushortT*)y)[(size_t)blockIdx.x * ystride + d] = (ushortT)f2bf(v);
    else       ((float*)y)  [(size_t)blockIdx.x * ystride + d] = v;
  }
}

// ---------- bf16 MFMA GEMM: C[m,n] = act( sum_k A[m,k]*W[n,k] + bias[n] ) (+resid) ----------
// m97 structure: 128x128 tile, BK=32, 4 waves (each 64x64), global_load_lds staging.
template<int OUTBF, int ACT, int HASRES>
__global__ __launch_bounds__(256) void gemm_mfma(
    const ushortT* __restrict__ A, const ushortT* __restrict__ W,
    const float* __restrict__ bias, const float* __restrict__ resid,
    void* __restrict__ Cout, int M, int N, int K)
{
  __shared__ ushortT As[128 * 32];  // 8 KB, row-major [row][k]
  __shared__ ushortT Ws[128 * 32];  // 8 KB, row-major [n-row][k]
  const int tid = threadIdx.x, lane = tid & 63, wid = tid >> 6;
  const int bm = blockIdx.y * 128, bn = blockIdx.x * 128;
  const int wm = (wid >> 1) * 64, wn = (wid & 1) * 64;

  // staging geometry: chunk c (1KB) covers rows [c*16, c*16+16); lane covers
  // row c*16 + (lane>>2), cols (lane&3)*8 .. +7. Wave w owns chunks {2w, 2w+1}.
  const int srow = lane >> 2;
  const int scol = (lane & 3) * 8;
  int arow0 = bm + (2 * wid) * 16 + srow;     if (arow0 > M - 1) arow0 = M - 1;
  int arow1 = bm + (2 * wid + 1) * 16 + srow; if (arow1 > M - 1) arow1 = M - 1;
  const int wrow0 = bn + (2 * wid) * 16 + srow;
  const int wrow1 = bn + (2 * wid + 1) * 16 + srow;
  const ushortT* aP0 = A + (size_t)arow0 * K + scol;
  const ushortT* aP1 = A + (size_t)arow1 * K + scol;
  const ushortT* wP0 = W + (size_t)wrow0 * K + scol;
  const ushortT* wP1 = W + (size_t)wrow1 * K + scol;
  ushortT* ldsA0 = As + (2 * wid) * 512;
  ushortT* ldsA1 = As + (2 * wid + 1) * 512;
  ushortT* ldsW0 = Ws + (2 * wid) * 512;
  ushortT* ldsW1 = Ws + (2 * wid + 1) * 512;

  f32x4 acc[4][4];
  #pragma unroll
  for (int i = 0; i < 4; i++)
    #pragma unroll
    for (int j = 0; j < 4; j++)
      acc[i][j] = (f32x4){0.f, 0.f, 0.f, 0.f};

  const int rsel = lane & 15, ksel = (lane >> 4) * 8;
  const int nk = K >> 5;
  for (int kt = 0; kt < nk; ++kt) {
    gload16(aP0, ldsA0); gload16(aP1, ldsA1);
    gload16(wP0, ldsW0); gload16(wP1, ldsW1);
    aP0 += 32; aP1 += 32; wP0 += 32; wP1 += 32;
    __syncthreads();
    bf16x8 af[4], bfr[4];
    #pragma unroll
    for (int i = 0; i < 4; i++)
      af[i] = *(const bf16x8*)(As + (wm + i * 16 + rsel) * 32 + ksel);
    #pragma unroll
    for (int j = 0; j < 4; j++)
      bfr[j] = *(const bf16x8*)(Ws + (wn + j * 16 + rsel) * 32 + ksel);
    #pragma unroll
    for (int i = 0; i < 4; i++)
      #pragma unroll
      for (int j = 0; j < 4; j++)
        acc[i][j] = __builtin_amdgcn_mfma_f32_16x16x32_bf16(af[i], bfr[j], acc[i][j], 0, 0, 0);
    __syncthreads();
  }

  // epilogue: C/D layout col=lane&15, row=(lane>>4)*4+reg
  const int crow = (lane >> 4) * 4, ccol = lane & 15;
  #pragma unroll
  for (int i = 0; i < 4; i++) {
    #pragma unroll
    for (int r = 0; r < 4; r++) {
      int m = bm + wm + i * 16 + crow + r;
      if (m < M) {
        #pragma unroll
        for (int j = 0; j < 4; j++) {
          int n = bn + wn + j * 16 + ccol;
          float v = acc[i][j][r];
          if (bias) v += bias[n];
          if (ACT) v = gelu_f(v);
          if (HASRES) v += resid[(size_t)m * N + n];
          if (OUTBF) ((ushortT*)Cout)[(size_t)m * N + n] = (ushortT)f2bf(v);
          else       ((float*)Cout)  [(size_t)m * N + n] = v;
        }
      }
    }
  }
}

// ---------- fused attention: one block per (b, head); qkv is bf16 ----------
__device__ inline float dot64(const float* q, const unsigned int* krow)
{
  float s = 0.f;
  const uint4* kp = (const uint4*)krow;
  #pragma unroll
  for (int w = 0; w < 8; w++) {
    uint4 u = kp[w];
    s = fmaf(q[w*8+0], bflo(u.x), s); s = fmaf(q[w*8+1], bfhi(u.x), s);
    s = fmaf(q[w*8+2], bflo(u.y), s); s = fmaf(q[w*8+3], bfhi(u.y), s);
    s = fmaf(q[w*8+4], bflo(u.z), s); s = fmaf(q[w*8+5], bfhi(u.z), s);
    s = fmaf(q[w*8+6], bflo(u.w), s); s = fmaf(q[w*8+7], bfhi(u.w), s);
  }
  return s;
}

__global__ __launch_bounds__(256) void attn_kernel(
    const ushortT* __restrict__ qkv, const float* __restrict__ prefix_k,
    const float* __restrict__ prefix_v, const float* __restrict__ act_scale,
    const int* __restrict__ task_id, ushortT* __restrict__ out,
    int layer, int hasprefix)
{
  __shared__ unsigned int Ks[PL_ + NTOK][HD_ / 2];
  __shared__ unsigned int Vs[PL_ + NTOK][HD_ / 2];
  const int b = blockIdx.x / H_, h = blockIdx.x % H_;
  const int Kt = hasprefix ? (PL_ + NTOK) : NTOK;

  int tsk = 0;
  if (hasprefix) {
    tsk = task_id[b];
    tsk = tsk < 0 ? 0 : (tsk > TASKS_ - 1 ? TASKS_ - 1 : tsk);
  }

  for (int idx = threadIdx.x; idx < Kt * (HD_ / 2); idx += 256) {
    int j = idx >> 5, dw = idx & 31, d = dw * 2;
    if (hasprefix && j < PL_) {
      size_t off = ((((size_t)layer * TASKS_ + tsk) * PL_ + j) * H_ + h) * HD_ + d;
      Ks[j][dw] = f2bf(prefix_k[off]) | (f2bf(prefix_k[off + 1]) << 16);
      Vs[j][dw] = f2bf(prefix_v[off]) | (f2bf(prefix_v[off + 1]) << 16);
    } else {
      int n = hasprefix ? (j - PL_) : j;
      size_t off = ((size_t)b * NTOK + n) * (3 * D_) + (size_t)h * HD_ + d;
      Ks[j][dw] = *(const unsigned int*)(qkv + off + D_);
      Vs[j][dw] = *(const unsigned int*)(qkv + off + 2 * D_);
    }
  }
  __syncthreads();

  const int qr = threadIdx.x;
  if (qr >= NTOK) return;

  float q[HD_];
  {
    const ushortT* qp = qkv + ((size_t)b * NTOK + qr) * (3 * D_) + (size_t)h * HD_;
    const uint4* qv = (const uint4*)qp;
    #pragma unroll
    for (int w = 0; w < 8; w++) {
      uint4 u = qv[w];
      q[w*8+0] = bflo(u.x) * SCALE_; q[w*8+1] = bfhi(u.x) * SCALE_;
      q[w*8+2] = bflo(u.y) * SCALE_; q[w*8+3] = bfhi(u.y) * SCALE_;
      q[w*8+4] = bflo(u.z) * SCALE_; q[w*8+5] = bfhi(u.z) * SCALE_;
      q[w*8+6] = bflo(u.w) * SCALE_; q[w*8+7] = bfhi(u.w) * SCALE_;
    }
  }
  float s0 = 1.f, s1 = 1.f;
  if (hasprefix) { s0 = act_scale[layer * 2]; s1 = act_scale[layer * 2 + 1]; }

  float mx = -1e30f;
  for (int j = 0; j < Kt; j++) {
    float s = dot64(q, Ks[j]);
    if (hasprefix && j < PL_) s += s1 / (1.f + __expf(-s * s0));
    mx = fmaxf(mx, s);
  }
  float l = 0.f;
  float o[HD_];
  #pragma unroll
  for (int d = 0; d < HD_; d++) o[d] = 0.f;
  for (int j = 0; j < Kt; j++) {
    float s = dot64(q, Ks[j]);
    if (hasprefix && j < PL_) s += s1 / (1.f + __expf(-s * s0));
    float p = __expf(s - mx);
    l += p;
    const uint4* vp = (const uint4*)Vs[j];
    #pragma unroll
    for (int w = 0; w < 8; w++) {
      uint4 u = vp[w];
      o[w*8+0] = fmaf(p, bflo(u.x), o[w*8+0]); o[w*8+1] = fmaf(p, bfhi(u.x), o[w*8+1]);
      o[w*8+2] = fmaf(p, bflo(u.y), o[w*8+2]); o[w*8+3] = fmaf(p, bfhi(u.y), o[w*8+3]);
      o[w*8+4] = fmaf(p, bflo(u.z), o[w*8+4]); o[w*8+5] = fmaf(p, bfhi(u.z), o[w*8+5]);
      o[w*8+6] = fmaf(p, bflo(u.w), o[w*8+6]); o[w*8+7] = fmaf(p, bfhi(u.w), o[w*8+7]);
    }
  }
  float inv = 1.f / l;
  ushortT* op = out + ((size_t)b * NTOK + qr) * D_ + (size_t)h * HD_;
  unsigned int* op32 = (unsigned int*)op;
  #pragma unroll
  for (int d = 0; d < HD_ / 2; d++)
    op32[d] = f2bf(o[2*d] * inv) | (f2bf(o[2*d+1] * inv) << 16);
}

// ---------- launch ----------
extern "C" void kernel_launch(void* const* d_in, const int* in_sizes, int n_in,
                              void* d_out, int out_size, void* d_ws, size_t ws_size,
                              hipStream_t stream)
{
  (void)in_sizes; (void)n_in; (void)out_size; (void)ws_size;
  const float* x         = (const float*)d_in[0];
  const int*   task_id   = (const int*)  d_in[1];
  const float* patch_w   = (const float*)d_in[2];
  const float* patch_b   = (const float*)d_in[3];
  const float* cls_token = (const float*)d_in[4];
  const float* pos_embed = (const float*)d_in[5];
  const float* ln1_w     = (const float*)d_in[6];
  const float* ln1_b     = (const float*)d_in[7];
  const float* qkv_w     = (const float*)d_in[8];
  const float* qkv_b     = (const float*)d_in[9];
  const float* proj_w    = (const float*)d_in[10];
  const float* proj_b    = (const float*)d_in[11];
  const float* ln2_w     = (const float*)d_in[12];
  const float* ln2_b     = (const float*)d_in[13];
  const float* fc1_w     = (const float*)d_in[14];
  const float* fc1_b     = (const float*)d_in[15];
  const float* fc2_w     = (const float*)d_in[16];
  const float* fc2_b     = (const float*)d_in[17];
  const float* norm_w    = (const float*)d_in[18];
  const float* norm_b    = (const float*)d_in[19];
  const float* prefix_k  = (const float*)d_in[20];
  const float* prefix_v  = (const float*)d_in[21];
  const float* act_scale = (const float*)d_in[22];
  float* out = (float*)d_out;

  // workspace layout (bytes):
  char* wsb = (char*)d_ws;
  float*   h      = (float*)  (wsb);                       // 6304*768*4  = 19,365,888
  ushortT* actA   = (ushortT*)(wsb + 19365888);            // 6304*768*2  =  9,682,944
  ushortT* qkvbuf = (ushortT*)(wsb + 29048832);            // 6304*2304*2 = 29,048,832
  ushortT* mlpbuf = (ushortT*)(wsb + 58097664);            // 6304*3072*2 = 38,731,776
  ushortT* wsc    = (ushortT*)(wsb + 96829440);            // 7,077,888*2 = 14,155,776
  float*   peout  = (float*)qkvbuf;                        // 6272*768*4 fits in qkvbuf

  ushortT* wqkv  = wsc;
  ushortT* wproj = wsc + 1769472;
  ushortT* wfc1  = wsc + 2359296;
  ushortT* wfc2  = wsc + 4718592;

  // ---- patch embedding ----
  convw1_kernel<<<288, 256, 0, stream>>>(patch_w, wsc, 73728);
  im2col_kernel<<<(B_ * NPATCH * D_ + 255) / 256, 256, 0, stream>>>(x, actA);
  gemm_mfma<0,0,0><<<dim3(6, 49), 256, 0, stream>>>(
      actA, wsc, nullptr, nullptr, peout, B_ * NPATCH, D_, D_);
  assemble_kernel<<<(ROWS * D_ + 255) / 256, 256, 0, stream>>>(
      peout, patch_b, cls_token, pos_embed, h);

  // ---- transformer layers ----
  for (int i = 0; i < DEPTH_; i++) {
    convw4_kernel<<<3456, 256, 0, stream>>>(
        qkv_w + (size_t)i * 1769472, proj_w + (size_t)i * 589824,
        fc1_w + (size_t)i * 2359296, fc2_w + (size_t)i * 2359296, wsc);
    ln_kernel<1><<<ROWS, 256, 0, stream>>>(h, D_, ln1_w + i * D_, ln1_b + i * D_, actA, D_);
    gemm_mfma<1,0,0><<<dim3(18, 50), 256, 0, stream>>>(
        actA, wqkv, qkv_b + i * 3 * D_, nullptr, qkvbuf, ROWS, 3 * D_, D_);
    int hp = (i < NPL_) ? 1 : 0;
    attn_kernel<<<B_ * H_, 256, 0, stream>>>(
        qkvbuf, prefix_k, prefix_v, act_scale, task_id, actA, i, hp);
    gemm_mfma<0,0,1><<<dim3(6, 50), 256, 0, stream>>>(
        actA, wproj, proj_b + i * D_, h, h, ROWS, D_, D_);
    ln_kernel<1><<<ROWS, 256, 0, stream>>>(h, D_, ln2_w + i * D_, ln2_b + i * D_, actA, D_);
    gemm_mfma<1,1,0><<<dim3(24, 50), 256, 0, stream>>>(
        actA, wfc1, fc1_b + i * MLPD_, nullptr, mlpbuf, ROWS, MLPD_, D_);
    gemm_mfma<0,0,1><<<dim3(6, 50), 256, 0, stream>>>(
        mlpbuf, wfc2, fc2_b + i * D_, h, h, ROWS, D_, MLPD_);
  }

  // ---- final LN on token 0 only ----
  ln_kernel<0><<<B_, 256, 0, stream>>>(h, (size_t)NTOK * D_, norm_w, norm_b, out, D_);
}

// Round 3
// 4223.721 us; speedup vs baseline: 6.1645x; 1.5911x over previous
//
#include <hip/hip_runtime.h>
#include <hip/hip_bf16.h>

#define B_     32
#define NTOK   197
#define NPATCH 196
#define D_     768
#define H_     12
#define HD_    64
#define DEPTH_ 12
#define MLPD_  3072
#define TASKS_ 10
#define PL_    5
#define NPL_   5
#define SCALE_ 0.125f
#define ROWS   (B_*NTOK)   // 6304

typedef unsigned short ushortT;
typedef __bf16 bf16x8 __attribute__((ext_vector_type(8)));
typedef float  f32x4  __attribute__((ext_vector_type(4)));

// ---------- helpers ----------
__device__ inline unsigned int f2bf(float f){
  unsigned int u = __float_as_uint(f);
  return (u + 0x7fffu + ((u >> 16) & 1u)) >> 16;   // RNE to bf16
}
__device__ inline float gelu_f(float x){ return 0.5f * x * (1.f + erff(x * 0.70710678118f)); }

__device__ inline void gload16(const void* g, void* l){
  __builtin_amdgcn_global_load_lds(
      (const __attribute__((address_space(1))) void*)(uintptr_t)g,
      (__attribute__((address_space(3))) void*)(uintptr_t)l,
      16, 0, 0);
}

// ---------- weight conversion fp32 -> bf16 ----------
__global__ __launch_bounds__(256) void convw4_kernel(const float* __restrict__ s0,
    const float* __restrict__ s1, const float* __restrict__ s2, const float* __restrict__ s3,
    ushortT* __restrict__ dst)
{
  int idx = blockIdx.x * 256 + threadIdx.x;
  int e = idx * 8;
  if (e >= 7077888) return;
  const float* s; int loc;
  if (e < 1769472)      { s = s0; loc = e; }
  else if (e < 2359296) { s = s1; loc = e - 1769472; }
  else if (e < 4718592) { s = s2; loc = e - 2359296; }
  else                  { s = s3; loc = e - 4718592; }
  float4 a = *(const float4*)(s + loc);
  float4 c = *(const float4*)(s + loc + 4);
  uint4 o;
  o.x = f2bf(a.x) | (f2bf(a.y) << 16);
  o.y = f2bf(a.z) | (f2bf(a.w) << 16);
  o.z = f2bf(c.x) | (f2bf(c.y) << 16);
  o.w = f2bf(c.z) | (f2bf(c.w) << 16);
  *(uint4*)(dst + e) = o;
}

__global__ __launch_bounds__(256) void convw1_kernel(const float* __restrict__ s,
    ushortT* __restrict__ dst, int n8)
{
  int idx = blockIdx.x * 256 + threadIdx.x;
  if (idx >= n8) return;
  int e = idx * 8;
  float4 a = *(const float4*)(s + e);
  float4 c = *(const float4*)(s + e + 4);
  uint4 o;
  o.x = f2bf(a.x) | (f2bf(a.y) << 16);
  o.y = f2bf(a.z) | (f2bf(a.w) << 16);
  o.z = f2bf(c.x) | (f2bf(c.y) << 16);
  o.w = f2bf(c.z) | (f2bf(c.w) << 16);
  *(uint4*)(dst + e) = o;
}

// ---------- im2col (bf16 out) ----------
__global__ __launch_bounds__(256) void im2col_kernel(const float* __restrict__ x,
                                                     ushortT* __restrict__ out)
{
  int idx = blockIdx.x * 256 + threadIdx.x;
  const int tot = B_ * NPATCH * D_;
  if (idx >= tot) return;
  int m = idx / D_, k = idx - m * D_;
  int b = m / NPATCH, p = m - b * NPATCH;
  int pr = p / 14, pc = p - pr * 14;
  int c = k >> 8, r = k & 255;
  int py = r >> 4, px = r & 15;
  float v = x[(((size_t)(b * 3 + c) * 224) + pr * 16 + py) * 224 + pc * 16 + px];
  out[idx] = (ushortT)f2bf(v);
}

// ---------- assemble h0 = [cls; patches+patch_b] + pos (fp32) ----------
__global__ __launch_bounds__(256) void assemble_kernel(const float* __restrict__ pe,
    const float* __restrict__ patch_b, const float* __restrict__ cls,
    const float* __restrict__ pos, float* __restrict__ h)
{
  int idx = blockIdx.x * 256 + threadIdx.x;
  const int tot = ROWS * D_;
  if (idx >= tot) return;
  int bn = idx / D_, d = idx - bn * D_;
  int b = bn / NTOK, n = bn - b * NTOK;
  float v;
  if (n == 0) v = cls[d];
  else        v = pe[((size_t)b * NPATCH + (n - 1)) * D_ + d] + patch_b[d];
  h[idx] = v + pos[(size_t)n * D_ + d];
}

// ---------- LayerNorm (one block per row), templated output ----------
template<int OUTBF>
__global__ __launch_bounds__(256) void ln_kernel(const float* __restrict__ x, size_t xstride,
    const float* __restrict__ w, const float* __restrict__ b,
    void* __restrict__ y, size_t ystride)
{
  const float* xr = x + (size_t)blockIdx.x * xstride;
  float vals[3];
  float s = 0.f, ss = 0.f;
  #pragma unroll
  for (int t = 0; t < 3; t++) {
    float v = xr[threadIdx.x + t * 256];
    vals[t] = v; s += v; ss += v * v;
  }
  #pragma unroll
  for (int off = 32; off >= 1; off >>= 1) {
    s  += __shfl_down(s, off);
    ss += __shfl_down(ss, off);
  }
  __shared__ float sm[4], ssm[4];
  int wid = threadIdx.x >> 6, lane = threadIdx.x & 63;
  if (lane == 0) { sm[wid] = s; ssm[wid] = ss; }
  __syncthreads();
  s  = sm[0] + sm[1] + sm[2] + sm[3];
  ss = ssm[0] + ssm[1] + ssm[2] + ssm[3];
  float mean = s * (1.f / D_);
  float var  = ss * (1.f / D_) - mean * mean;
  float inv  = rsqrtf(var + 1e-6f);
  #pragma unroll
  for (int t = 0; t < 3; t++) {
    int d = threadIdx.x + t * 256;
    float v = (vals[t] - mean) * inv * w[d] + b[d];
    if (OUTBF) ((ushortT*)y)[(size_t)blockIdx.x * ystride + d] = (ushortT)f2bf(v);
    else       ((float*)y)  [(size_t)blockIdx.x * ystride + d] = v;
  }
}

// ---------- bf16 MFMA GEMM (m97 structure, unchanged from round 2) ----------
template<int OUTBF, int ACT, int HASRES>
__global__ __launch_bounds__(256) void gemm_mfma(
    const ushortT* __restrict__ A, const ushortT* __restrict__ W,
    const float* __restrict__ bias, const float* __restrict__ resid,
    void* __restrict__ Cout, int M, int N, int K)
{
  __shared__ ushortT As[128 * 32];
  __shared__ ushortT Ws[128 * 32];
  const int tid = threadIdx.x, lane = tid & 63, wid = tid >> 6;
  const int bm = blockIdx.y * 128, bn = blockIdx.x * 128;
  const int wm = (wid >> 1) * 64, wn = (wid & 1) * 64;

  const int srow = lane >> 2;
  const int scol = (lane & 3) * 8;
  int arow0 = bm + (2 * wid) * 16 + srow;     if (arow0 > M - 1) arow0 = M - 1;
  int arow1 = bm + (2 * wid + 1) * 16 + srow; if (arow1 > M - 1) arow1 = M - 1;
  const int wrow0 = bn + (2 * wid) * 16 + srow;
  const int wrow1 = bn + (2 * wid + 1) * 16 + srow;
  const ushortT* aP0 = A + (size_t)arow0 * K + scol;
  const ushortT* aP1 = A + (size_t)arow1 * K + scol;
  const ushortT* wP0 = W + (size_t)wrow0 * K + scol;
  const ushortT* wP1 = W + (size_t)wrow1 * K + scol;
  ushortT* ldsA0 = As + (2 * wid) * 512;
  ushortT* ldsA1 = As + (2 * wid + 1) * 512;
  ushortT* ldsW0 = Ws + (2 * wid) * 512;
  ushortT* ldsW1 = Ws + (2 * wid + 1) * 512;

  f32x4 acc[4][4];
  #pragma unroll
  for (int i = 0; i < 4; i++)
    #pragma unroll
    for (int j = 0; j < 4; j++)
      acc[i][j] = (f32x4){0.f, 0.f, 0.f, 0.f};

  const int rsel = lane & 15, ksel = (lane >> 4) * 8;
  const int nk = K >> 5;
  for (int kt = 0; kt < nk; ++kt) {
    gload16(aP0, ldsA0); gload16(aP1, ldsA1);
    gload16(wP0, ldsW0); gload16(wP1, ldsW1);
    aP0 += 32; aP1 += 32; wP0 += 32; wP1 += 32;
    __syncthreads();
    bf16x8 af[4], bfr[4];
    #pragma unroll
    for (int i = 0; i < 4; i++)
      af[i] = *(const bf16x8*)(As + (wm + i * 16 + rsel) * 32 + ksel);
    #pragma unroll
    for (int j = 0; j < 4; j++)
      bfr[j] = *(const bf16x8*)(Ws + (wn + j * 16 + rsel) * 32 + ksel);
    #pragma unroll
    for (int i = 0; i < 4; i++)
      #pragma unroll
      for (int j = 0; j < 4; j++)
        acc[i][j] = __builtin_amdgcn_mfma_f32_16x16x32_bf16(af[i], bfr[j], acc[i][j], 0, 0, 0);
    __syncthreads();
  }

  const int crow = (lane >> 4) * 4, ccol = lane & 15;
  #pragma unroll
  for (int i = 0; i < 4; i++) {
    #pragma unroll
    for (int r = 0; r < 4; r++) {
      int m = bm + wm + i * 16 + crow + r;
      if (m < M) {
        #pragma unroll
        for (int j = 0; j < 4; j++) {
          int n = bn + wn + j * 16 + ccol;
          float v = acc[i][j][r];
          if (bias) v += bias[n];
          if (ACT) v = gelu_f(v);
          if (HASRES) v += resid[(size_t)m * N + n];
          if (OUTBF) ((ushortT*)Cout)[(size_t)m * N + n] = (ushortT)f2bf(v);
          else       ((float*)Cout)  [(size_t)m * N + n] = v;
        }
      }
    }
  }
}

// ---------- MFMA attention ----------
// Grid (2, H, B). Per block: stage K [208][64] bf16 XOR-swizzled, Vt [64][232] bf16.
// Per 16-row q-tile: S^T = mfma(K, Q) -> lane holds q=lane&15, k rows (g*4+r)/tile;
// in-reg softmax (52 vals + shfl_xor 16/32); P -> per-wave LDS slab -> A-frag; O = mfma(P, Vt).
#define KROWS 208
#define VSTR  232
__global__ __launch_bounds__(256) void attn_mfma(
    const ushortT* __restrict__ qkv, const float* __restrict__ prefix_k,
    const float* __restrict__ prefix_v, const float* __restrict__ act_scale,
    const int* __restrict__ task_id, ushortT* __restrict__ out,
    int layer, int koff)
{
  __shared__ ushortT smem[13312 + 14848 + 4096];   // 64512 B
  ushortT* Kl = smem;             // [208][64] swizzled
  ushortT* Vt = smem + 13312;     // [64][232]
  ushortT* Ps = smem + 13312 + 14848;  // 4 waves x 2 x [16][32]

  const int tid = threadIdx.x, lane = tid & 63, wid = tid >> 6;
  const int g = lane >> 4, qc = lane & 15;
  const int qh = blockIdx.x, h = blockIdx.y, b = blockIdx.z;
  const int KtA = NTOK + koff;

  int tsk = 0;
  float s0 = 1.f, s1 = 1.f;
  if (koff) {
    tsk = task_id[b]; tsk = tsk < 0 ? 0 : (tsk > TASKS_ - 1 ? TASKS_ - 1 : tsk);
    s0 = act_scale[layer * 2]; s1 = act_scale[layer * 2 + 1];
  }

  // zero Vt fully + K pad rows (avoid NaN garbage in padded mfma operands)
  {
    uint4* vz = (uint4*)Vt;
    for (int i = tid; i < 14848 / 8; i += 256) vz[i] = (uint4){0, 0, 0, 0};
    uint4* kz = (uint4*)(Kl + 202 * 64);
    if (tid < 48) kz[tid] = (uint4){0, 0, 0, 0};
  }
  __syncthreads();

  // stage K (swizzled row-major) and V (transposed)
  for (int u = tid; u < KtA * 8; u += 256) {
    int row = u >> 3, cg = u & 7;
    uint4 val;
    if (row < koff) {
      size_t off = ((((size_t)layer * TASKS_ + tsk) * PL_ + row) * H_ + h) * HD_ + cg * 8;
      float4 f0 = *(const float4*)(prefix_k + off);
      float4 f1 = *(const float4*)(prefix_k + off + 4);
      val.x = f2bf(f0.x) | (f2bf(f0.y) << 16); val.y = f2bf(f0.z) | (f2bf(f0.w) << 16);
      val.z = f2bf(f1.x) | (f2bf(f1.y) << 16); val.w = f2bf(f1.z) | (f2bf(f1.w) << 16);
    } else {
      int n = row - koff;
      val = *(const uint4*)(qkv + ((size_t)b * NTOK + n) * 2304 + D_ + h * HD_ + cg * 8);
    }
    *(uint4*)(Kl + row * 64 + ((cg * 8) ^ ((row & 7) << 3))) = val;
  }
  for (int u = tid; u < KtA * 8; u += 256) {
    int row = u >> 3, dg = u & 7;
    ushortT e[8];
    if (row < koff) {
      size_t off = ((((size_t)layer * TASKS_ + tsk) * PL_ + row) * H_ + h) * HD_ + dg * 8;
      #pragma unroll
      for (int t = 0; t < 8; t++) e[t] = (ushortT)f2bf(prefix_v[off + t]);
    } else {
      int n = row - koff;
      uint4 v = *(const uint4*)(qkv + ((size_t)b * NTOK + n) * 2304 + 2 * D_ + h * HD_ + dg * 8);
      *(uint4*)e = v;
    }
    #pragma unroll
    for (int t = 0; t < 8; t++) Vt[(dg * 8 + t) * VSTR + row] = e[t];
  }
  __syncthreads();

  const int tend = qh ? 13 : 7;
  for (int t = qh * 7 + wid; t < tend; t += 4) {
    const int q0 = t * 16;
    int qr = q0 + qc; if (qr > NTOK - 1) qr = NTOK - 1;
    const ushortT* qp = qkv + ((size_t)b * NTOK + qr) * 2304 + h * HD_ + g * 8;
    bf16x8 qf0 = *(const bf16x8*)qp;
    bf16x8 qf1 = *(const bf16x8*)(qp + 32);

    // S^T = K · Q^T
    f32x4 sacc[13];
    #pragma unroll
    for (int kt = 0; kt < 13; kt++) sacc[kt] = (f32x4){0.f, 0.f, 0.f, 0.f};
    #pragma unroll
    for (int kt = 0; kt < 13; kt++) {
      int row = kt * 16 + qc;
      int sw = (row & 7) << 3;
      bf16x8 ka0 = *(const bf16x8*)(Kl + row * 64 + ((g * 8) ^ sw));
      bf16x8 ka1 = *(const bf16x8*)(Kl + row * 64 + ((32 + g * 8) ^ sw));
      sacc[kt] = __builtin_amdgcn_mfma_f32_16x16x32_bf16(ka0, qf0, sacc[kt], 0, 0, 0);
      sacc[kt] = __builtin_amdgcn_mfma_f32_16x16x32_bf16(ka1, qf1, sacc[kt], 0, 0, 0);
    }

    // softmax over k (per q-row): lane holds k = kt*16 + g*4 + r
    float* sp = (float*)sacc;
    float mx = -1e30f;
    #pragma unroll
    for (int kt = 0; kt < 13; kt++)
      #pragma unroll
      for (int r = 0; r < 4; r++) {
        int k = kt * 16 + g * 4 + r;
        float s = sp[kt * 4 + r] * SCALE_;
        if (koff && k < PL_) s += s1 / (1.f + __expf(-s * s0));
        if (k >= KtA) s = -1e30f;
        sp[kt * 4 + r] = s;
        mx = fmaxf(mx, s);
      }
    mx = fmaxf(mx, __shfl_xor(mx, 16));
    mx = fmaxf(mx, __shfl_xor(mx, 32));
    float sum = 0.f;
    #pragma unroll
    for (int i = 0; i < 52; i++) { float p = __expf(sp[i] - mx); sp[i] = p; sum += p; }
    sum += __shfl_xor(sum, 16);
    sum += __shfl_xor(sum, 32);
    const float inv = 1.f / sum;

    // PV: per 32-k chunk, re-layout P via per-wave slab, O += mfma(P, Vt)
    f32x4 oacc[4];
    #pragma unroll
    for (int d = 0; d < 4; d++) oacc[d] = (f32x4){0.f, 0.f, 0.f, 0.f};
    #pragma unroll
    for (int c = 0; c < 7; c++) {
      ushortT* slab = Ps + wid * 1024 + (c & 1) * 512;
      uint2 w0, w1;
      {
        float p0 = sp[8 * c + 0] * inv, p1 = sp[8 * c + 1] * inv;
        float p2 = sp[8 * c + 2] * inv, p3 = sp[8 * c + 3] * inv;
        w0.x = f2bf(p0) | (f2bf(p1) << 16); w0.y = f2bf(p2) | (f2bf(p3) << 16);
      }
      if (c < 6) {
        float p0 = sp[8 * c + 4] * inv, p1 = sp[8 * c + 5] * inv;
        float p2 = sp[8 * c + 6] * inv, p3 = sp[8 * c + 7] * inv;
        w1.x = f2bf(p0) | (f2bf(p1) << 16); w1.y = f2bf(p2) | (f2bf(p3) << 16);
      } else { w1.x = 0; w1.y = 0; }
      *(uint2*)(slab + qc * 32 + g * 4) = w0;
      *(uint2*)(slab + qc * 32 + 16 + g * 4) = w1;
      bf16x8 pa = *(const bf16x8*)(slab + qc * 32 + g * 8);
      #pragma unroll
      for (int dt = 0; dt < 4; dt++) {
        bf16x8 vb = *(const bf16x8*)(Vt + (dt * 16 + qc) * VSTR + c * 32 + g * 8);
        oacc[dt] = __builtin_amdgcn_mfma_f32_16x16x32_bf16(pa, vb, oacc[dt], 0, 0, 0);
      }
    }

    // store O: lane holds O[q = g*4+r][d = dt*16 + qc]
    #pragma unroll
    for (int r = 0; r < 4; r++) {
      int q = q0 + g * 4 + r;
      if (q < NTOK) {
        size_t ro = ((size_t)b * NTOK + q) * D_ + h * HD_;
        #pragma unroll
        for (int dt = 0; dt < 4; dt++)
          out[ro + dt * 16 + qc] = (ushortT)f2bf(oacc[dt][r]);
      }
    }
  }
}

// ---------- launch ----------
extern "C" void kernel_launch(void* const* d_in, const int* in_sizes, int n_in,
                              void* d_out, int out_size, void* d_ws, size_t ws_size,
                              hipStream_t stream)
{
  (void)in_sizes; (void)n_in; (void)out_size; (void)ws_size;
  const float* x         = (const float*)d_in[0];
  const int*   task_id   = (const int*)  d_in[1];
  const float* patch_w   = (const float*)d_in[2];
  const float* patch_b   = (const float*)d_in[3];
  const float* cls_token = (const float*)d_in[4];
  const float* pos_embed = (const float*)d_in[5];
  const float* ln1_w     = (const float*)d_in[6];
  const float* ln1_b     = (const float*)d_in[7];
  const float* qkv_w     = (const float*)d_in[8];
  const float* qkv_b     = (const float*)d_in[9];
  const float* proj_w    = (const float*)d_in[10];
  const float* proj_b    = (const float*)d_in[11];
  const float* ln2_w     = (const float*)d_in[12];
  const float* ln2_b     = (const float*)d_in[13];
  const float* fc1_w     = (const float*)d_in[14];
  const float* fc1_b     = (const float*)d_in[15];
  const float* fc2_w     = (const float*)d_in[16];
  const float* fc2_b     = (const float*)d_in[17];
  const float* norm_w    = (const float*)d_in[18];
  const float* norm_b    = (const float*)d_in[19];
  const float* prefix_k  = (const float*)d_in[20];
  const float* prefix_v  = (const float*)d_in[21];
  const float* act_scale = (const float*)d_in[22];
  float* out = (float*)d_out;

  char* wsb = (char*)d_ws;
  float*   h      = (float*)  (wsb);                       // 19,365,888
  ushortT* actA   = (ushortT*)(wsb + 19365888);            //  9,682,944
  ushortT* qkvbuf = (ushortT*)(wsb + 29048832);            // 29,048,832
  ushortT* mlpbuf = (ushortT*)(wsb + 58097664);            // 38,731,776
  ushortT* wsc    = (ushortT*)(wsb + 96829440);            // 14,155,776
  float*   peout  = (float*)qkvbuf;

  ushortT* wqkv  = wsc;
  ushortT* wproj = wsc + 1769472;
  ushortT* wfc1  = wsc + 2359296;
  ushortT* wfc2  = wsc + 4718592;

  // ---- patch embedding ----
  convw1_kernel<<<288, 256, 0, stream>>>(patch_w, wsc, 73728);
  im2col_kernel<<<(B_ * NPATCH * D_ + 255) / 256, 256, 0, stream>>>(x, actA);
  gemm_mfma<0,0,0><<<dim3(6, 49), 256, 0, stream>>>(
      actA, wsc, nullptr, nullptr, peout, B_ * NPATCH, D_, D_);
  assemble_kernel<<<(ROWS * D_ + 255) / 256, 256, 0, stream>>>(
      peout, patch_b, cls_token, pos_embed, h);

  // ---- transformer layers ----
  for (int i = 0; i < DEPTH_; i++) {
    convw4_kernel<<<3456, 256, 0, stream>>>(
        qkv_w + (size_t)i * 1769472, proj_w + (size_t)i * 589824,
        fc1_w + (size_t)i * 2359296, fc2_w + (size_t)i * 2359296, wsc);
    ln_kernel<1><<<ROWS, 256, 0, stream>>>(h, D_, ln1_w + i * D_, ln1_b + i * D_, actA, D_);
    gemm_mfma<1,0,0><<<dim3(18, 50), 256, 0, stream>>>(
        actA, wqkv, qkv_b + i * 3 * D_, nullptr, qkvbuf, ROWS, 3 * D_, D_);
    attn_mfma<<<dim3(2, H_, B_), 256, 0, stream>>>(
        qkvbuf, prefix_k, prefix_v, act_scale, task_id, actA, i, (i < NPL_) ? PL_ : 0);
    gemm_mfma<0,0,1><<<dim3(6, 50), 256, 0, stream>>>(
        actA, wproj, proj_b + i * D_, h, h, ROWS, D_, D_);
    ln_kernel<1><<<ROWS, 256, 0, stream>>>(h, D_, ln2_w + i * D_, ln2_b + i * D_, actA, D_);
    gemm_mfma<1,1,0><<<dim3(24, 50), 256, 0, stream>>>(
        actA, wfc1, fc1_b + i * MLPD_, nullptr, mlpbuf, ROWS, MLPD_, D_);
    gemm_mfma<0,0,1><<<dim3(6, 50), 256, 0, stream>>>(
        mlpbuf, wfc2, fc2_b + i * D_, h, h, ROWS, D_, MLPD_);
  }

  ln_kernel<0><<<B_, 256, 0, stream>>>(h, (size_t)NTOK * D_, norm_w, norm_b, out, D_);
}

// Round 4
// 3791.822 us; speedup vs baseline: 6.8666x; 1.1139x over previous
//
#include <hip/hip_runtime.h>
#include <hip/hip_bf16.h>

#define B_     32
#define NTOK   197
#define NPATCH 196
#define D_     768
#define H_     12
#define HD_    64
#define DEPTH_ 12
#define MLPD_  3072
#define TASKS_ 10
#define PL_    5
#define NPL_   5
#define SCALE_ 0.125f
#define ROWS   (B_*NTOK)   // 6304

typedef unsigned short ushortT;
typedef __bf16 bf16x8 __attribute__((ext_vector_type(8)));
typedef float  f32x4  __attribute__((ext_vector_type(4)));

// ---------- helpers ----------
__device__ inline unsigned int f2bf(float f){
  unsigned int u = __float_as_uint(f);
  return (u + 0x7fffu + ((u >> 16) & 1u)) >> 16;   // RNE to bf16
}
__device__ inline float gelu_f(float x){ return 0.5f * x * (1.f + erff(x * 0.70710678118f)); }

__device__ inline void gload16(const void* g, void* l){
  __builtin_amdgcn_global_load_lds(
      (const __attribute__((address_space(1))) void*)(uintptr_t)g,
      (__attribute__((address_space(3))) void*)(uintptr_t)l,
      16, 0, 0);
}

// ---------- weight conversion fp32 -> bf16 ----------
__global__ __launch_bounds__(256) void convw4_kernel(const float* __restrict__ s0,
    const float* __restrict__ s1, const float* __restrict__ s2, const float* __restrict__ s3,
    ushortT* __restrict__ dst)
{
  int idx = blockIdx.x * 256 + threadIdx.x;
  int e = idx * 8;
  if (e >= 7077888) return;
  const float* s; int loc;
  if (e < 1769472)      { s = s0; loc = e; }
  else if (e < 2359296) { s = s1; loc = e - 1769472; }
  else if (e < 4718592) { s = s2; loc = e - 2359296; }
  else                  { s = s3; loc = e - 4718592; }
  float4 a = *(const float4*)(s + loc);
  float4 c = *(const float4*)(s + loc + 4);
  uint4 o;
  o.x = f2bf(a.x) | (f2bf(a.y) << 16);
  o.y = f2bf(a.z) | (f2bf(a.w) << 16);
  o.z = f2bf(c.x) | (f2bf(c.y) << 16);
  o.w = f2bf(c.z) | (f2bf(c.w) << 16);
  *(uint4*)(dst + e) = o;
}

__global__ __launch_bounds__(256) void convw1_kernel(const float* __restrict__ s,
    ushortT* __restrict__ dst, int n8)
{
  int idx = blockIdx.x * 256 + threadIdx.x;
  if (idx >= n8) return;
  int e = idx * 8;
  float4 a = *(const float4*)(s + e);
  float4 c = *(const float4*)(s + e + 4);
  uint4 o;
  o.x = f2bf(a.x) | (f2bf(a.y) << 16);
  o.y = f2bf(a.z) | (f2bf(a.w) << 16);
  o.z = f2bf(c.x) | (f2bf(c.y) << 16);
  o.w = f2bf(c.z) | (f2bf(c.w) << 16);
  *(uint4*)(dst + e) = o;
}

// ---------- im2col (bf16 out) ----------
__global__ __launch_bounds__(256) void im2col_kernel(const float* __restrict__ x,
                                                     ushortT* __restrict__ out)
{
  int idx = blockIdx.x * 256 + threadIdx.x;
  const int tot = B_ * NPATCH * D_;
  if (idx >= tot) return;
  int m = idx / D_, k = idx - m * D_;
  int b = m / NPATCH, p = m - b * NPATCH;
  int pr = p / 14, pc = p - pr * 14;
  int c = k >> 8, r = k & 255;
  int py = r >> 4, px = r & 15;
  float v = x[(((size_t)(b * 3 + c) * 224) + pr * 16 + py) * 224 + pc * 16 + px];
  out[idx] = (ushortT)f2bf(v);
}

// ---------- assemble h0 = [cls; patches+patch_b] + pos (fp32) ----------
__global__ __launch_bounds__(256) void assemble_kernel(const float* __restrict__ pe,
    const float* __restrict__ patch_b, const float* __restrict__ cls,
    const float* __restrict__ pos, float* __restrict__ h)
{
  int idx = blockIdx.x * 256 + threadIdx.x;
  const int tot = ROWS * D_;
  if (idx >= tot) return;
  int bn = idx / D_, d = idx - bn * D_;
  int b = bn / NTOK, n = bn - b * NTOK;
  float v;
  if (n == 0) v = cls[d];
  else        v = pe[((size_t)b * NPATCH + (n - 1)) * D_ + d] + patch_b[d];
  h[idx] = v + pos[(size_t)n * D_ + d];
}

// ---------- LayerNorm (one block per row), templated output ----------
template<int OUTBF>
__global__ __launch_bounds__(256) void ln_kernel(const float* __restrict__ x, size_t xstride,
    const float* __restrict__ w, const float* __restrict__ b,
    void* __restrict__ y, size_t ystride)
{
  const float* xr = x + (size_t)blockIdx.x * xstride;
  float vals[3];
  float s = 0.f, ss = 0.f;
  #pragma unroll
  for (int t = 0; t < 3; t++) {
    float v = xr[threadIdx.x + t * 256];
    vals[t] = v; s += v; ss += v * v;
  }
  #pragma unroll
  for (int off = 32; off >= 1; off >>= 1) {
    s  += __shfl_down(s, off);
    ss += __shfl_down(ss, off);
  }
  __shared__ float sm[4], ssm[4];
  int wid = threadIdx.x >> 6, lane = threadIdx.x & 63;
  if (lane == 0) { sm[wid] = s; ssm[wid] = ss; }
  __syncthreads();
  s  = sm[0] + sm[1] + sm[2] + sm[3];
  ss = ssm[0] + ssm[1] + ssm[2] + ssm[3];
  float mean = s * (1.f / D_);
  float var  = ss * (1.f / D_) - mean * mean;
  float inv  = rsqrtf(var + 1e-6f);
  #pragma unroll
  for (int t = 0; t < 3; t++) {
    int d = threadIdx.x + t * 256;
    float v = (vals[t] - mean) * inv * w[d] + b[d];
    if (OUTBF) ((ushortT*)y)[(size_t)blockIdx.x * ystride + d] = (ushortT)f2bf(v);
    else       ((float*)y)  [(size_t)blockIdx.x * ystride + d] = v;
  }
}

// ---------- bf16 MFMA GEMM: 128x128 tile, BK=32, DOUBLE-BUFFERED (T3-min 2-phase) ----------
// Per K-step: issue next-tile global_load_lds BEFORE ds_read+MFMA of current tile;
// single vmcnt(0)-drain barrier (__syncthreads) per K-step after MFMAs.
template<int OUTBF, int ACT, int HASRES>
__global__ __launch_bounds__(256) void gemm_mfma(
    const ushortT* __restrict__ A, const ushortT* __restrict__ W,
    const float* __restrict__ bias, const float* __restrict__ resid,
    void* __restrict__ Cout, int M, int N, int K)
{
  __shared__ ushortT As[2][128 * 32];   // 2 x 8 KB
  __shared__ ushortT Ws[2][128 * 32];   // 2 x 8 KB
  const int tid = threadIdx.x, lane = tid & 63, wid = tid >> 6;
  const int bm = blockIdx.y * 128, bn = blockIdx.x * 128;
  const int wm = (wid >> 1) * 64, wn = (wid & 1) * 64;

  // staging geometry: chunk c (1KB) covers rows [c*16, c*16+16); lane covers
  // row c*16 + (lane>>2), cols (lane&3)*8 .. +7. Wave w owns chunks {2w, 2w+1}.
  const int srow = lane >> 2;
  const int scol = (lane & 3) * 8;
  int arow0 = bm + (2 * wid) * 16 + srow;     if (arow0 > M - 1) arow0 = M - 1;
  int arow1 = bm + (2 * wid + 1) * 16 + srow; if (arow1 > M - 1) arow1 = M - 1;
  const int wrow0 = bn + (2 * wid) * 16 + srow;
  const int wrow1 = bn + (2 * wid + 1) * 16 + srow;
  const ushortT* aP0 = A + (size_t)arow0 * K + scol;
  const ushortT* aP1 = A + (size_t)arow1 * K + scol;
  const ushortT* wP0 = W + (size_t)wrow0 * K + scol;
  const ushortT* wP1 = W + (size_t)wrow1 * K + scol;
  const int c0 = (2 * wid) * 512, c1 = (2 * wid + 1) * 512;

  f32x4 acc[4][4];
  #pragma unroll
  for (int i = 0; i < 4; i++)
    #pragma unroll
    for (int j = 0; j < 4; j++)
      acc[i][j] = (f32x4){0.f, 0.f, 0.f, 0.f};

  const int rsel = lane & 15, ksel = (lane >> 4) * 8;
  const int nk = K >> 5;

  // prologue: stage K-step 0 into buffer 0, drain
  gload16(aP0, As[0] + c0); gload16(aP1, As[0] + c1);
  gload16(wP0, Ws[0] + c0); gload16(wP1, Ws[0] + c1);
  __syncthreads();

  for (int kt = 0; kt < nk; ++kt) {
    const int cur = kt & 1;
    // issue next-tile loads into the other buffer (in flight across ds_read+MFMA)
    if (kt + 1 < nk) {
      const int off = (kt + 1) * 32;
      gload16(aP0 + off, As[cur ^ 1] + c0); gload16(aP1 + off, As[cur ^ 1] + c1);
      gload16(wP0 + off, Ws[cur ^ 1] + c0); gload16(wP1 + off, Ws[cur ^ 1] + c1);
    }
    bf16x8 af[4], bfr[4];
    #pragma unroll
    for (int i = 0; i < 4; i++)
      af[i] = *(const bf16x8*)(As[cur] + (wm + i * 16 + rsel) * 32 + ksel);
    #pragma unroll
    for (int j = 0; j < 4; j++)
      bfr[j] = *(const bf16x8*)(Ws[cur] + (wn + j * 16 + rsel) * 32 + ksel);
    #pragma unroll
    for (int i = 0; i < 4; i++)
      #pragma unroll
      for (int j = 0; j < 4; j++)
        acc[i][j] = __builtin_amdgcn_mfma_f32_16x16x32_bf16(af[i], bfr[j], acc[i][j], 0, 0, 0);
    __syncthreads();   // drains vmcnt(0)+lgkmcnt(0): next tile staged, this tile consumed
  }

  // epilogue: C/D layout col=lane&15, row=(lane>>4)*4+reg
  const int crow = (lane >> 4) * 4, ccol = lane & 15;
  #pragma unroll
  for (int i = 0; i < 4; i++) {
    #pragma unroll
    for (int r = 0; r < 4; r++) {
      int m = bm + wm + i * 16 + crow + r;
      if (m < M) {
        #pragma unroll
        for (int j = 0; j < 4; j++) {
          int n = bn + wn + j * 16 + ccol;
          float v = acc[i][j][r];
          if (bias) v += bias[n];
          if (ACT) v = gelu_f(v);
          if (HASRES) v += resid[(size_t)m * N + n];
          if (OUTBF) ((ushortT*)Cout)[(size_t)m * N + n] = (ushortT)f2bf(v);
          else       ((float*)Cout)  [(size_t)m * N + n] = v;
        }
      }
    }
  }
}

// ---------- MFMA attention (unchanged from round 3) ----------
#define KROWS 208
#define VSTR  232
__global__ __launch_bounds__(256) void attn_mfma(
    const ushortT* __restrict__ qkv, const float* __restrict__ prefix_k,
    const float* __restrict__ prefix_v, const float* __restrict__ act_scale,
    const int* __restrict__ task_id, ushortT* __restrict__ out,
    int layer, int koff)
{
  __shared__ ushortT smem[13312 + 14848 + 4096];   // 64512 B
  ushortT* Kl = smem;             // [208][64] swizzled
  ushortT* Vt = smem + 13312;     // [64][232]
  ushortT* Ps = smem + 13312 + 14848;  // 4 waves x 2 x [16][32]

  const int tid = threadIdx.x, lane = tid & 63, wid = tid >> 6;
  const int g = lane >> 4, qc = lane & 15;
  const int qh = blockIdx.x, h = blockIdx.y, b = blockIdx.z;
  const int KtA = NTOK + koff;

  int tsk = 0;
  float s0 = 1.f, s1 = 1.f;
  if (koff) {
    tsk = task_id[b]; tsk = tsk < 0 ? 0 : (tsk > TASKS_ - 1 ? TASKS_ - 1 : tsk);
    s0 = act_scale[layer * 2]; s1 = act_scale[layer * 2 + 1];
  }

  {
    uint4* vz = (uint4*)Vt;
    for (int i = tid; i < 14848 / 8; i += 256) vz[i] = (uint4){0, 0, 0, 0};
    uint4* kz = (uint4*)(Kl + 202 * 64);
    if (tid < 48) kz[tid] = (uint4){0, 0, 0, 0};
  }
  __syncthreads();

  for (int u = tid; u < KtA * 8; u += 256) {
    int row = u >> 3, cg = u & 7;
    uint4 val;
    if (row < koff) {
      size_t off = ((((size_t)layer * TASKS_ + tsk) * PL_ + row) * H_ + h) * HD_ + cg * 8;
      float4 f0 = *(const float4*)(prefix_k + off);
      float4 f1 = *(const float4*)(prefix_k + off + 4);
      val.x = f2bf(f0.x) | (f2bf(f0.y) << 16); val.y = f2bf(f0.z) | (f2bf(f0.w) << 16);
      val.z = f2bf(f1.x) | (f2bf(f1.y) << 16); val.w = f2bf(f1.z) | (f2bf(f1.w) << 16);
    } else {
      int n = row - koff;
      val = *(const uint4*)(qkv + ((size_t)b * NTOK + n) * 2304 + D_ + h * HD_ + cg * 8);
    }
    *(uint4*)(Kl + row * 64 + ((cg * 8) ^ ((row & 7) << 3))) = val;
  }
  for (int u = tid; u < KtA * 8; u += 256) {
    int row = u >> 3, dg = u & 7;
    ushortT e[8];
    if (row < koff) {
      size_t off = ((((size_t)layer * TASKS_ + tsk) * PL_ + row) * H_ + h) * HD_ + dg * 8;
      #pragma unroll
      for (int t = 0; t < 8; t++) e[t] = (ushortT)f2bf(prefix_v[off + t]);
    } else {
      int n = row - koff;
      uint4 v = *(const uint4*)(qkv + ((size_t)b * NTOK + n) * 2304 + 2 * D_ + h * HD_ + dg * 8);
      *(uint4*)e = v;
    }
    #pragma unroll
    for (int t = 0; t < 8; t++) Vt[(dg * 8 + t) * VSTR + row] = e[t];
  }
  __syncthreads();

  const int tend = qh ? 13 : 7;
  for (int t = qh * 7 + wid; t < tend; t += 4) {
    const int q0 = t * 16;
    int qr = q0 + qc; if (qr > NTOK - 1) qr = NTOK - 1;
    const ushortT* qp = qkv + ((size_t)b * NTOK + qr) * 2304 + h * HD_ + g * 8;
    bf16x8 qf0 = *(const bf16x8*)qp;
    bf16x8 qf1 = *(const bf16x8*)(qp + 32);

    f32x4 sacc[13];
    #pragma unroll
    for (int kt = 0; kt < 13; kt++) sacc[kt] = (f32x4){0.f, 0.f, 0.f, 0.f};
    #pragma unroll
    for (int kt = 0; kt < 13; kt++) {
      int row = kt * 16 + qc;
      int sw = (row & 7) << 3;
      bf16x8 ka0 = *(const bf16x8*)(Kl + row * 64 + ((g * 8) ^ sw));
      bf16x8 ka1 = *(const bf16x8*)(Kl + row * 64 + ((32 + g * 8) ^ sw));
      sacc[kt] = __builtin_amdgcn_mfma_f32_16x16x32_bf16(ka0, qf0, sacc[kt], 0, 0, 0);
      sacc[kt] = __builtin_amdgcn_mfma_f32_16x16x32_bf16(ka1, qf1, sacc[kt], 0, 0, 0);
    }

    float* sp = (float*)sacc;
    float mx = -1e30f;
    #pragma unroll
    for (int kt = 0; kt < 13; kt++)
      #pragma unroll
      for (int r = 0; r < 4; r++) {
        int k = kt * 16 + g * 4 + r;
        float s = sp[kt * 4 + r] * SCALE_;
        if (koff && k < PL_) s += s1 / (1.f + __expf(-s * s0));
        if (k >= KtA) s = -1e30f;
        sp[kt * 4 + r] = s;
        mx = fmaxf(mx, s);
      }
    mx = fmaxf(mx, __shfl_xor(mx, 16));
    mx = fmaxf(mx, __shfl_xor(mx, 32));
    float sum = 0.f;
    #pragma unroll
    for (int i = 0; i < 52; i++) { float p = __expf(sp[i] - mx); sp[i] = p; sum += p; }
    sum += __shfl_xor(sum, 16);
    sum += __shfl_xor(sum, 32);
    const float inv = 1.f / sum;

    f32x4 oacc[4];
    #pragma unroll
    for (int d = 0; d < 4; d++) oacc[d] = (f32x4){0.f, 0.f, 0.f, 0.f};
    #pragma unroll
    for (int c = 0; c < 7; c++) {
      ushortT* slab = Ps + wid * 1024 + (c & 1) * 512;
      uint2 w0, w1;
      {
        float p0 = sp[8 * c + 0] * inv, p1 = sp[8 * c + 1] * inv;
        float p2 = sp[8 * c + 2] * inv, p3 = sp[8 * c + 3] * inv;
        w0.x = f2bf(p0) | (f2bf(p1) << 16); w0.y = f2bf(p2) | (f2bf(p3) << 16);
      }
      if (c < 6) {
        float p0 = sp[8 * c + 4] * inv, p1 = sp[8 * c + 5] * inv;
        float p2 = sp[8 * c + 6] * inv, p3 = sp[8 * c + 7] * inv;
        w1.x = f2bf(p0) | (f2bf(p1) << 16); w1.y = f2bf(p2) | (f2bf(p3) << 16);
      } else { w1.x = 0; w1.y = 0; }
      *(uint2*)(slab + qc * 32 + g * 4) = w0;
      *(uint2*)(slab + qc * 32 + 16 + g * 4) = w1;
      bf16x8 pa = *(const bf16x8*)(slab + qc * 32 + g * 8);
      #pragma unroll
      for (int dt = 0; dt < 4; dt++) {
        bf16x8 vb = *(const bf16x8*)(Vt + (dt * 16 + qc) * VSTR + c * 32 + g * 8);
        oacc[dt] = __builtin_amdgcn_mfma_f32_16x16x32_bf16(pa, vb, oacc[dt], 0, 0, 0);
      }
    }

    #pragma unroll
    for (int r = 0; r < 4; r++) {
      int q = q0 + g * 4 + r;
      if (q < NTOK) {
        size_t ro = ((size_t)b * NTOK + q) * D_ + h * HD_;
        #pragma unroll
        for (int dt = 0; dt < 4; dt++)
          out[ro + dt * 16 + qc] = (ushortT)f2bf(oacc[dt][r]);
      }
    }
  }
}

// ---------- launch ----------
extern "C" void kernel_launch(void* const* d_in, const int* in_sizes, int n_in,
                              void* d_out, int out_size, void* d_ws, size_t ws_size,
                              hipStream_t stream)
{
  (void)in_sizes; (void)n_in; (void)out_size; (void)ws_size;
  const float* x         = (const float*)d_in[0];
  const int*   task_id   = (const int*)  d_in[1];
  const float* patch_w   = (const float*)d_in[2];
  const float* patch_b   = (const float*)d_in[3];
  const float* cls_token = (const float*)d_in[4];
  const float* pos_embed = (const float*)d_in[5];
  const float* ln1_w     = (const float*)d_in[6];
  const float* ln1_b     = (const float*)d_in[7];
  const float* qkv_w     = (const float*)d_in[8];
  const float* qkv_b     = (const float*)d_in[9];
  const float* proj_w    = (const float*)d_in[10];
  const float* proj_b    = (const float*)d_in[11];
  const float* ln2_w     = (const float*)d_in[12];
  const float* ln2_b     = (const float*)d_in[13];
  const float* fc1_w     = (const float*)d_in[14];
  const float* fc1_b     = (const float*)d_in[15];
  const float* fc2_w     = (const float*)d_in[16];
  const float* fc2_b     = (const float*)d_in[17];
  const float* norm_w    = (const float*)d_in[18];
  const float* norm_b    = (const float*)d_in[19];
  const float* prefix_k  = (const float*)d_in[20];
  const float* prefix_v  = (const float*)d_in[21];
  const float* act_scale = (const float*)d_in[22];
  float* out = (float*)d_out;

  char* wsb = (char*)d_ws;
  float*   h      = (float*)  (wsb);                       // 19,365,888
  ushortT* actA   = (ushortT*)(wsb + 19365888);            //  9,682,944
  ushortT* qkvbuf = (ushortT*)(wsb + 29048832);            // 29,048,832
  ushortT* mlpbuf = (ushortT*)(wsb + 58097664);            // 38,731,776
  ushortT* wsc    = (ushortT*)(wsb + 96829440);            // 14,155,776
  float*   peout  = (float*)qkvbuf;

  ushortT* wqkv  = wsc;
  ushortT* wproj = wsc + 1769472;
  ushortT* wfc1  = wsc + 2359296;
  ushortT* wfc2  = wsc + 4718592;

  // ---- patch embedding ----
  convw1_kernel<<<288, 256, 0, stream>>>(patch_w, wsc, 73728);
  im2col_kernel<<<(B_ * NPATCH * D_ + 255) / 256, 256, 0, stream>>>(x, actA);
  gemm_mfma<0,0,0><<<dim3(6, 49), 256, 0, stream>>>(
      actA, wsc, nullptr, nullptr, peout, B_ * NPATCH, D_, D_);
  assemble_kernel<<<(ROWS * D_ + 255) / 256, 256, 0, stream>>>(
      peout, patch_b, cls_token, pos_embed, h);

  // ---- transformer layers ----
  for (int i = 0; i < DEPTH_; i++) {
    convw4_kernel<<<3456, 256, 0, stream>>>(
        qkv_w + (size_t)i * 1769472, proj_w + (size_t)i * 589824,
        fc1_w + (size_t)i * 2359296, fc2_w + (size_t)i * 2359296, wsc);
    ln_kernel<1><<<ROWS, 256, 0, stream>>>(h, D_, ln1_w + i * D_, ln1_b + i * D_, actA, D_);
    gemm_mfma<1,0,0><<<dim3(18, 50), 256, 0, stream>>>(
        actA, wqkv, qkv_b + i * 3 * D_, nullptr, qkvbuf, ROWS, 3 * D_, D_);
    attn_mfma<<<dim3(2, H_, B_), 256, 0, stream>>>(
        qkvbuf, prefix_k, prefix_v, act_scale, task_id, actA, i, (i < NPL_) ? PL_ : 0);
    gemm_mfma<0,0,1><<<dim3(6, 50), 256, 0, stream>>>(
        actA, wproj, proj_b + i * D_, h, h, ROWS, D_, D_);
    ln_kernel<1><<<ROWS, 256, 0, stream>>>(h, D_, ln2_w + i * D_, ln2_b + i * D_, actA, D_);
    gemm_mfma<1,1,0><<<dim3(24, 50), 256, 0, stream>>>(
        actA, wfc1, fc1_b + i * MLPD_, nullptr, mlpbuf, ROWS, MLPD_, D_);
    gemm_mfma<0,0,1><<<dim3(6, 50), 256, 0, stream>>>(
        mlpbuf, wfc2, fc2_b + i * D_, h, h, ROWS, D_, MLPD_);
  }

  ln_kernel<0><<<B_, 256, 0, stream>>>(h, (size_t)NTOK * D_, norm_w, norm_b, out, D_);
}

// Round 5
// 3754.982 us; speedup vs baseline: 6.9340x; 1.0098x over previous
//
#include <hip/hip_runtime.h>
#include <hip/hip_bf16.h>

#define B_     32
#define NTOK   197
#define NPATCH 196
#define D_     768
#define H_     12
#define HD_    64
#define DEPTH_ 12
#define MLPD_  3072
#define TASKS_ 10
#define PL_    5
#define NPL_   5
#define SCALE_ 0.125f
#define ROWS   (B_*NTOK)   // 6304

typedef unsigned short ushortT;
typedef __bf16 bf16x8 __attribute__((ext_vector_type(8)));
typedef float  f32x4  __attribute__((ext_vector_type(4)));

// ---------- helpers ----------
__device__ inline unsigned int f2bf(float f){
  unsigned int u = __float_as_uint(f);
  return (u + 0x7fffu + ((u >> 16) & 1u)) >> 16;   // RNE to bf16
}
__device__ inline float gelu_f(float x){ return 0.5f * x * (1.f + erff(x * 0.70710678118f)); }

__device__ inline void gload16(const void* g, void* l){
  __builtin_amdgcn_global_load_lds(
      (const __attribute__((address_space(1))) void*)(uintptr_t)g,
      (__attribute__((address_space(3))) void*)(uintptr_t)l,
      16, 0, 0);
}

// ---------- weight conversion fp32 -> bf16 ----------
__global__ __launch_bounds__(256) void convw4_kernel(const float* __restrict__ s0,
    const float* __restrict__ s1, const float* __restrict__ s2, const float* __restrict__ s3,
    ushortT* __restrict__ dst)
{
  int idx = blockIdx.x * 256 + threadIdx.x;
  int e = idx * 8;
  if (e >= 7077888) return;
  const float* s; int loc;
  if (e < 1769472)      { s = s0; loc = e; }
  else if (e < 2359296) { s = s1; loc = e - 1769472; }
  else if (e < 4718592) { s = s2; loc = e - 2359296; }
  else                  { s = s3; loc = e - 4718592; }
  float4 a = *(const float4*)(s + loc);
  float4 c = *(const float4*)(s + loc + 4);
  uint4 o;
  o.x = f2bf(a.x) | (f2bf(a.y) << 16);
  o.y = f2bf(a.z) | (f2bf(a.w) << 16);
  o.z = f2bf(c.x) | (f2bf(c.y) << 16);
  o.w = f2bf(c.z) | (f2bf(c.w) << 16);
  *(uint4*)(dst + e) = o;
}

__global__ __launch_bounds__(256) void convw1_kernel(const float* __restrict__ s,
    ushortT* __restrict__ dst, int n8)
{
  int idx = blockIdx.x * 256 + threadIdx.x;
  if (idx >= n8) return;
  int e = idx * 8;
  float4 a = *(const float4*)(s + e);
  float4 c = *(const float4*)(s + e + 4);
  uint4 o;
  o.x = f2bf(a.x) | (f2bf(a.y) << 16);
  o.y = f2bf(a.z) | (f2bf(a.w) << 16);
  o.z = f2bf(c.x) | (f2bf(c.y) << 16);
  o.w = f2bf(c.z) | (f2bf(c.w) << 16);
  *(uint4*)(dst + e) = o;
}

// ---------- im2col (bf16 out) ----------
__global__ __launch_bounds__(256) void im2col_kernel(const float* __restrict__ x,
                                                     ushortT* __restrict__ out)
{
  int idx = blockIdx.x * 256 + threadIdx.x;
  const int tot = B_ * NPATCH * D_;
  if (idx >= tot) return;
  int m = idx / D_, k = idx - m * D_;
  int b = m / NPATCH, p = m - b * NPATCH;
  int pr = p / 14, pc = p - pr * 14;
  int c = k >> 8, r = k & 255;
  int py = r >> 4, px = r & 15;
  float v = x[(((size_t)(b * 3 + c) * 224) + pr * 16 + py) * 224 + pc * 16 + px];
  out[idx] = (ushortT)f2bf(v);
}

// ---------- assemble h0 = [cls; patches+patch_b] + pos (fp32) ----------
__global__ __launch_bounds__(256) void assemble_kernel(const float* __restrict__ pe,
    const float* __restrict__ patch_b, const float* __restrict__ cls,
    const float* __restrict__ pos, float* __restrict__ h)
{
  int idx = blockIdx.x * 256 + threadIdx.x;
  const int tot = ROWS * D_;
  if (idx >= tot) return;
  int bn = idx / D_, d = idx - bn * D_;
  int b = bn / NTOK, n = bn - b * NTOK;
  float v;
  if (n == 0) v = cls[d];
  else        v = pe[((size_t)b * NPATCH + (n - 1)) * D_ + d] + patch_b[d];
  h[idx] = v + pos[(size_t)n * D_ + d];
}

// ---------- LayerNorm (one block per row), templated output ----------
template<int OUTBF>
__global__ __launch_bounds__(256) void ln_kernel(const float* __restrict__ x, size_t xstride,
    const float* __restrict__ w, const float* __restrict__ b,
    void* __restrict__ y, size_t ystride)
{
  const float* xr = x + (size_t)blockIdx.x * xstride;
  float vals[3];
  float s = 0.f, ss = 0.f;
  #pragma unroll
  for (int t = 0; t < 3; t++) {
    float v = xr[threadIdx.x + t * 256];
    vals[t] = v; s += v; ss += v * v;
  }
  #pragma unroll
  for (int off = 32; off >= 1; off >>= 1) {
    s  += __shfl_down(s, off);
    ss += __shfl_down(ss, off);
  }
  __shared__ float sm[4], ssm[4];
  int wid = threadIdx.x >> 6, lane = threadIdx.x & 63;
  if (lane == 0) { sm[wid] = s; ssm[wid] = ss; }
  __syncthreads();
  s  = sm[0] + sm[1] + sm[2] + sm[3];
  ss = ssm[0] + ssm[1] + ssm[2] + ssm[3];
  float mean = s * (1.f / D_);
  float var  = ss * (1.f / D_) - mean * mean;
  float inv  = rsqrtf(var + 1e-6f);
  #pragma unroll
  for (int t = 0; t < 3; t++) {
    int d = threadIdx.x + t * 256;
    float v = (vals[t] - mean) * inv * w[d] + b[d];
    if (OUTBF) ((ushortT*)y)[(size_t)blockIdx.x * ystride + d] = (ushortT)f2bf(v);
    else       ((float*)y)  [(size_t)blockIdx.x * ystride + d] = v;
  }
}

// ---------- bf16 MFMA GEMM: 128x128 tile, BK=32, depth-2 pipeline, counted vmcnt (T4) ----------
// 3 LDS buffers; per K-step: s_waitcnt vmcnt(8) [tiles t+1,t+2 stay in flight across the
// raw s_barrier] -> ds_read+MFMA -> s_barrier -> issue stage(t+3) into retired buffer.
// Tail issues dummy tile-0 loads into dead buffers to keep vmcnt immediate uniform.
template<int OUTBF, int ACT, int HASRES>
__global__ __launch_bounds__(256, 3) void gemm_mfma(
    const ushortT* __restrict__ A, const ushortT* __restrict__ W,
    const float* __restrict__ bias, const float* __restrict__ resid,
    void* __restrict__ Cout, int M, int N, int K)
{
  __shared__ ushortT As[3][4096];   // 3 x 8 KB
  __shared__ ushortT Ws[3][4096];   // 3 x 8 KB
  const int tid = threadIdx.x, lane = tid & 63, wid = tid >> 6;
  const int bm = blockIdx.y * 128, bn = blockIdx.x * 128;
  const int wm = (wid >> 1) * 64, wn = (wid & 1) * 64;

  // staging geometry: chunk c (1KB) covers rows [c*16, c*16+16); lane covers
  // row c*16 + (lane>>2), cols (lane&3)*8 .. +7. Wave w owns chunks {2w, 2w+1}.
  const int srow = lane >> 2;
  const int scol = (lane & 3) * 8;
  int arow0 = bm + (2 * wid) * 16 + srow;     if (arow0 > M - 1) arow0 = M - 1;
  int arow1 = bm + (2 * wid + 1) * 16 + srow; if (arow1 > M - 1) arow1 = M - 1;
  const int wrow0 = bn + (2 * wid) * 16 + srow;
  const int wrow1 = bn + (2 * wid + 1) * 16 + srow;
  const ushortT* aP0 = A + (size_t)arow0 * K + scol;
  const ushortT* aP1 = A + (size_t)arow1 * K + scol;
  const ushortT* wP0 = W + (size_t)wrow0 * K + scol;
  const ushortT* wP1 = W + (size_t)wrow1 * K + scol;
  const int c0 = (2 * wid) * 512, c1 = (2 * wid + 1) * 512;

  f32x4 acc[4][4];
  #pragma unroll
  for (int i = 0; i < 4; i++)
    #pragma unroll
    for (int j = 0; j < 4; j++)
      acc[i][j] = (f32x4){0.f, 0.f, 0.f, 0.f};

  const int rsel = lane & 15, ksel = (lane >> 4) * 8;
  const int nk = K >> 5;

  // prologue: stage tiles 0,1,2 into buffers 0,1,2 (12 loads/wave in flight)
  #pragma unroll
  for (int p = 0; p < 3; ++p) {
    const int off = p * 32;
    gload16(aP0 + off, As[p] + c0); gload16(aP1 + off, As[p] + c1);
    gload16(wP0 + off, Ws[p] + c0); gload16(wP1 + off, Ws[p] + c1);
  }

  int cb = 0;
  for (int kt = 0; kt < nk; ++kt) {
    // wait for tile kt only (8 = tiles kt+1, kt+2 remain outstanding)
    asm volatile("s_waitcnt vmcnt(8)" ::: "memory");
    __builtin_amdgcn_sched_barrier(0);
    __builtin_amdgcn_s_barrier();          // all waves' tile-kt writes visible

    bf16x8 af[4], bfr[4];
    #pragma unroll
    for (int i = 0; i < 4; i++)
      af[i] = *(const bf16x8*)(As[cb] + (wm + i * 16 + rsel) * 32 + ksel);
    #pragma unroll
    for (int j = 0; j < 4; j++)
      bfr[j] = *(const bf16x8*)(Ws[cb] + (wn + j * 16 + rsel) * 32 + ksel);
    #pragma unroll
    for (int i = 0; i < 4; i++)
      #pragma unroll
      for (int j = 0; j < 4; j++)
        acc[i][j] = __builtin_amdgcn_mfma_f32_16x16x32_bf16(af[i], bfr[j], acc[i][j], 0, 0, 0);

    __builtin_amdgcn_s_barrier();          // all waves done reading buf cb

    // refill retired buffer with tile kt+3 (dummy tile-0 reload at tail keeps vmcnt uniform)
    const int nt = kt + 3;
    const int off = (nt < nk) ? nt * 32 : 0;
    gload16(aP0 + off, As[cb] + c0); gload16(aP1 + off, As[cb] + c1);
    gload16(wP0 + off, Ws[cb] + c0); gload16(wP1 + off, Ws[cb] + c1);

    cb = (cb == 2) ? 0 : cb + 1;
  }

  // epilogue: C/D layout col=lane&15, row=(lane>>4)*4+reg
  const int crow = (lane >> 4) * 4, ccol = lane & 15;
  #pragma unroll
  for (int i = 0; i < 4; i++) {
    #pragma unroll
    for (int r = 0; r < 4; r++) {
      int m = bm + wm + i * 16 + crow + r;
      if (m < M) {
        #pragma unroll
        for (int j = 0; j < 4; j++) {
          int n = bn + wn + j * 16 + ccol;
          float v = acc[i][j][r];
          if (bias) v += bias[n];
          if (ACT) v = gelu_f(v);
          if (HASRES) v += resid[(size_t)m * N + n];
          if (OUTBF) ((ushortT*)Cout)[(size_t)m * N + n] = (ushortT)f2bf(v);
          else       ((float*)Cout)  [(size_t)m * N + n] = v;
        }
      }
    }
  }
}

// ---------- MFMA attention (unchanged) ----------
#define KROWS 208
#define VSTR  232
__global__ __launch_bounds__(256) void attn_mfma(
    const ushortT* __restrict__ qkv, const float* __restrict__ prefix_k,
    const float* __restrict__ prefix_v, const float* __restrict__ act_scale,
    const int* __restrict__ task_id, ushortT* __restrict__ out,
    int layer, int koff)
{
  __shared__ ushortT smem[13312 + 14848 + 4096];   // 64512 B
  ushortT* Kl = smem;             // [208][64] swizzled
  ushortT* Vt = smem + 13312;     // [64][232]
  ushortT* Ps = smem + 13312 + 14848;  // 4 waves x 2 x [16][32]

  const int tid = threadIdx.x, lane = tid & 63, wid = tid >> 6;
  const int g = lane >> 4, qc = lane & 15;
  const int qh = blockIdx.x, h = blockIdx.y, b = blockIdx.z;
  const int KtA = NTOK + koff;

  int tsk = 0;
  float s0 = 1.f, s1 = 1.f;
  if (koff) {
    tsk = task_id[b]; tsk = tsk < 0 ? 0 : (tsk > TASKS_ - 1 ? TASKS_ - 1 : tsk);
    s0 = act_scale[layer * 2]; s1 = act_scale[layer * 2 + 1];
  }

  {
    uint4* vz = (uint4*)Vt;
    for (int i = tid; i < 14848 / 8; i += 256) vz[i] = (uint4){0, 0, 0, 0};
    uint4* kz = (uint4*)(Kl + 202 * 64);
    if (tid < 48) kz[tid] = (uint4){0, 0, 0, 0};
  }
  __syncthreads();

  for (int u = tid; u < KtA * 8; u += 256) {
    int row = u >> 3, cg = u & 7;
    uint4 val;
    if (row < koff) {
      size_t off = ((((size_t)layer * TASKS_ + tsk) * PL_ + row) * H_ + h) * HD_ + cg * 8;
      float4 f0 = *(const float4*)(prefix_k + off);
      float4 f1 = *(const float4*)(prefix_k + off + 4);
      val.x = f2bf(f0.x) | (f2bf(f0.y) << 16); val.y = f2bf(f0.z) | (f2bf(f0.w) << 16);
      val.z = f2bf(f1.x) | (f2bf(f1.y) << 16); val.w = f2bf(f1.z) | (f2bf(f1.w) << 16);
    } else {
      int n = row - koff;
      val = *(const uint4*)(qkv + ((size_t)b * NTOK + n) * 2304 + D_ + h * HD_ + cg * 8);
    }
    *(uint4*)(Kl + row * 64 + ((cg * 8) ^ ((row & 7) << 3))) = val;
  }
  for (int u = tid; u < KtA * 8; u += 256) {
    int row = u >> 3, dg = u & 7;
    ushortT e[8];
    if (row < koff) {
      size_t off = ((((size_t)layer * TASKS_ + tsk) * PL_ + row) * H_ + h) * HD_ + dg * 8;
      #pragma unroll
      for (int t = 0; t < 8; t++) e[t] = (ushortT)f2bf(prefix_v[off + t]);
    } else {
      int n = row - koff;
      uint4 v = *(const uint4*)(qkv + ((size_t)b * NTOK + n) * 2304 + 2 * D_ + h * HD_ + dg * 8);
      *(uint4*)e = v;
    }
    #pragma unroll
    for (int t = 0; t < 8; t++) Vt[(dg * 8 + t) * VSTR + row] = e[t];
  }
  __syncthreads();

  const int tend = qh ? 13 : 7;
  for (int t = qh * 7 + wid; t < tend; t += 4) {
    const int q0 = t * 16;
    int qr = q0 + qc; if (qr > NTOK - 1) qr = NTOK - 1;
    const ushortT* qp = qkv + ((size_t)b * NTOK + qr) * 2304 + h * HD_ + g * 8;
    bf16x8 qf0 = *(const bf16x8*)qp;
    bf16x8 qf1 = *(const bf16x8*)(qp + 32);

    f32x4 sacc[13];
    #pragma unroll
    for (int kt = 0; kt < 13; kt++) sacc[kt] = (f32x4){0.f, 0.f, 0.f, 0.f};
    #pragma unroll
    for (int kt = 0; kt < 13; kt++) {
      int row = kt * 16 + qc;
      int sw = (row & 7) << 3;
      bf16x8 ka0 = *(const bf16x8*)(Kl + row * 64 + ((g * 8) ^ sw));
      bf16x8 ka1 = *(const bf16x8*)(Kl + row * 64 + ((32 + g * 8) ^ sw));
      sacc[kt] = __builtin_amdgcn_mfma_f32_16x16x32_bf16(ka0, qf0, sacc[kt], 0, 0, 0);
      sacc[kt] = __builtin_amdgcn_mfma_f32_16x16x32_bf16(ka1, qf1, sacc[kt], 0, 0, 0);
    }

    float* sp = (float*)sacc;
    float mx = -1e30f;
    #pragma unroll
    for (int kt = 0; kt < 13; kt++)
      #pragma unroll
      for (int r = 0; r < 4; r++) {
        int k = kt * 16 + g * 4 + r;
        float s = sp[kt * 4 + r] * SCALE_;
        if (koff && k < PL_) s += s1 / (1.f + __expf(-s * s0));
        if (k >= KtA) s = -1e30f;
        sp[kt * 4 + r] = s;
        mx = fmaxf(mx, s);
      }
    mx = fmaxf(mx, __shfl_xor(mx, 16));
    mx = fmaxf(mx, __shfl_xor(mx, 32));
    float sum = 0.f;
    #pragma unroll
    for (int i = 0; i < 52; i++) { float p = __expf(sp[i] - mx); sp[i] = p; sum += p; }
    sum += __shfl_xor(sum, 16);
    sum += __shfl_xor(sum, 32);
    const float inv = 1.f / sum;

    f32x4 oacc[4];
    #pragma unroll
    for (int d = 0; d < 4; d++) oacc[d] = (f32x4){0.f, 0.f, 0.f, 0.f};
    #pragma unroll
    for (int c = 0; c < 7; c++) {
      ushortT* slab = Ps + wid * 1024 + (c & 1) * 512;
      uint2 w0, w1;
      {
        float p0 = sp[8 * c + 0] * inv, p1 = sp[8 * c + 1] * inv;
        float p2 = sp[8 * c + 2] * inv, p3 = sp[8 * c + 3] * inv;
        w0.x = f2bf(p0) | (f2bf(p1) << 16); w0.y = f2bf(p2) | (f2bf(p3) << 16);
      }
      if (c < 6) {
        float p0 = sp[8 * c + 4] * inv, p1 = sp[8 * c + 5] * inv;
        float p2 = sp[8 * c + 6] * inv, p3 = sp[8 * c + 7] * inv;
        w1.x = f2bf(p0) | (f2bf(p1) << 16); w1.y = f2bf(p2) | (f2bf(p3) << 16);
      } else { w1.x = 0; w1.y = 0; }
      *(uint2*)(slab + qc * 32 + g * 4) = w0;
      *(uint2*)(slab + qc * 32 + 16 + g * 4) = w1;
      bf16x8 pa = *(const bf16x8*)(slab + qc * 32 + g * 8);
      #pragma unroll
      for (int dt = 0; dt < 4; dt++) {
        bf16x8 vb = *(const bf16x8*)(Vt + (dt * 16 + qc) * VSTR + c * 32 + g * 8);
        oacc[dt] = __builtin_amdgcn_mfma_f32_16x16x32_bf16(pa, vb, oacc[dt], 0, 0, 0);
      }
    }

    #pragma unroll
    for (int r = 0; r < 4; r++) {
      int q = q0 + g * 4 + r;
      if (q < NTOK) {
        size_t ro = ((size_t)b * NTOK + q) * D_ + h * HD_;
        #pragma unroll
        for (int dt = 0; dt < 4; dt++)
          out[ro + dt * 16 + qc] = (ushortT)f2bf(oacc[dt][r]);
      }
    }
  }
}

// ---------- launch ----------
extern "C" void kernel_launch(void* const* d_in, const int* in_sizes, int n_in,
                              void* d_out, int out_size, void* d_ws, size_t ws_size,
                              hipStream_t stream)
{
  (void)in_sizes; (void)n_in; (void)out_size; (void)ws_size;
  const float* x         = (const float*)d_in[0];
  const int*   task_id   = (const int*)  d_in[1];
  const float* patch_w   = (const float*)d_in[2];
  const float* patch_b   = (const float*)d_in[3];
  const float* cls_token = (const float*)d_in[4];
  const float* pos_embed = (const float*)d_in[5];
  const float* ln1_w     = (const float*)d_in[6];
  const float* ln1_b     = (const float*)d_in[7];
  const float* qkv_w     = (const float*)d_in[8];
  const float* qkv_b     = (const float*)d_in[9];
  const float* proj_w    = (const float*)d_in[10];
  const float* proj_b    = (const float*)d_in[11];
  const float* ln2_w     = (const float*)d_in[12];
  const float* ln2_b     = (const float*)d_in[13];
  const float* fc1_w     = (const float*)d_in[14];
  const float* fc1_b     = (const float*)d_in[15];
  const float* fc2_w     = (const float*)d_in[16];
  const float* fc2_b     = (const float*)d_in[17];
  const float* norm_w    = (const float*)d_in[18];
  const float* norm_b    = (const float*)d_in[19];
  const float* prefix_k  = (const float*)d_in[20];
  const float* prefix_v  = (const float*)d_in[21];
  const float* act_scale = (const float*)d_in[22];
  float* out = (float*)d_out;

  char* wsb = (char*)d_ws;
  float*   h      = (float*)  (wsb);                       // 19,365,888
  ushortT* actA   = (ushortT*)(wsb + 19365888);            //  9,682,944
  ushortT* qkvbuf = (ushortT*)(wsb + 29048832);            // 29,048,832
  ushortT* mlpbuf = (ushortT*)(wsb + 58097664);            // 38,731,776
  ushortT* wsc    = (ushortT*)(wsb + 96829440);            // 14,155,776
  float*   peout  = (float*)qkvbuf;

  ushortT* wqkv  = wsc;
  ushortT* wproj = wsc + 1769472;
  ushortT* wfc1  = wsc + 2359296;
  ushortT* wfc2  = wsc + 4718592;

  // ---- patch embedding ----
  convw1_kernel<<<288, 256, 0, stream>>>(patch_w, wsc, 73728);
  im2col_kernel<<<(B_ * NPATCH * D_ + 255) / 256, 256, 0, stream>>>(x, actA);
  gemm_mfma<0,0,0><<<dim3(6, 49), 256, 0, stream>>>(
      actA, wsc, nullptr, nullptr, peout, B_ * NPATCH, D_, D_);
  assemble_kernel<<<(ROWS * D_ + 255) / 256, 256, 0, stream>>>(
      peout, patch_b, cls_token, pos_embed, h);

  // ---- transformer layers ----
  for (int i = 0; i < DEPTH_; i++) {
    convw4_kernel<<<3456, 256, 0, stream>>>(
        qkv_w + (size_t)i * 1769472, proj_w + (size_t)i * 589824,
        fc1_w + (size_t)i * 2359296, fc2_w + (size_t)i * 2359296, wsc);
    ln_kernel<1><<<ROWS, 256, 0, stream>>>(h, D_, ln1_w + i * D_, ln1_b + i * D_, actA, D_);
    gemm_mfma<1,0,0><<<dim3(18, 50), 256, 0, stream>>>(
        actA, wqkv, qkv_b + i * 3 * D_, nullptr, qkvbuf, ROWS, 3 * D_, D_);
    attn_mfma<<<dim3(2, H_, B_), 256, 0, stream>>>(
        qkvbuf, prefix_k, prefix_v, act_scale, task_id, actA, i, (i < NPL_) ? PL_ : 0);
    gemm_mfma<0,0,1><<<dim3(6, 50), 256, 0, stream>>>(
        actA, wproj, proj_b + i * D_, h, h, ROWS, D_, D_);
    ln_kernel<1><<<ROWS, 256, 0, stream>>>(h, D_, ln2_w + i * D_, ln2_b + i * D_, actA, D_);
    gemm_mfma<1,1,0><<<dim3(24, 50), 256, 0, stream>>>(
        actA, wfc1, fc1_b + i * MLPD_, nullptr, mlpbuf, ROWS, MLPD_, D_);
    gemm_mfma<0,0,1><<<dim3(6, 50), 256, 0, stream>>>(
        mlpbuf, wfc2, fc2_b + i * D_, h, h, ROWS, D_, MLPD_);
  }

  ln_kernel<0><<<B_, 256, 0, stream>>>(h, (size_t)NTOK * D_, norm_w, norm_b, out, D_);
}